// Round 2
// baseline (593.165 us; speedup 1.0000x reference)
//
#include <hip/hip_runtime.h>
#include <hip/hip_bf16.h>

#define HH 448
#define WW 448
#define HWP (HH*WW)
#define CC 32
#define NN 20000
#define BB 4
#define PBLK 256
#define ABLK 256

// SHIFTS = [[0,0],[-1,0],[1,0],[0,1],[-1,1],[1,1],[0,-1],[-1,-1],[1,-1]]
__constant__ int c_SY[9] = {0,-1,1,0,-1,1,0,-1,1};
__constant__ int c_SX[9] = {0,0,0,1,1,1,-1,-1,-1};

// Per-direction fused weight block layout (floats), stride 4608:
// [0:1024]  WqT : WqT[t*32+i] = (wq@qkv_w0)[i][t]
// [1024:2048] WkT, [2048:3072] WvT
// [3072:4096] WoT : WoT[j*32+c] = out_w[c][j]
// [4096] bq_f(32) [4128] bk_f(32) [4160] bv_f(32) [4192] out_b(32)
// [4224] bk_raw(32) [4256] bv_raw(32) [4288:4576] posv(9x32)
#define WB_STRIDE 4608

static __device__ __forceinline__ float bf(const __hip_bfloat16 v) {
    return __bfloat162float(v);
}

// dtype-agnostic load: isf32 ? float[i] : bf16[i]
static __device__ __forceinline__ float ldf(const void* p, int i, int isf32) {
    if (isf32) return ((const float*)p)[i];
    return __bfloat162float(((const __hip_bfloat16*)p)[i]);
}

// Detect whether float tensors are stored as f32 or bf16.
// If data is f32, even-index 16-bit words are mantissa low-halves: exponents
// uniform-random -> ~23% land in the "sane" range. Real bf16 ~N(0,1) data: ~100%.
__global__ void sniff_kernel(const void* __restrict__ feats, int* __restrict__ flag) {
    __shared__ int cnt[256];
    const unsigned short u = ((const unsigned short*)feats)[threadIdx.x * 2];
    const int e = (u >> 7) & 0xFF;
    cnt[threadIdx.x] = (u == 0 || (e >= 97 && e <= 157)) ? 1 : 0;
    __syncthreads();
    for (int s = 128; s > 0; s >>= 1) {
        if (threadIdx.x < s) cnt[threadIdx.x] += cnt[threadIdx.x + s];
        __syncthreads();
    }
    if (threadIdx.x == 0) *flag = (cnt[0] >= 192) ? 0 : 1;   // 1 => f32
}

__global__ void prep_weights(const void* __restrict__ qkv1_w, const void* __restrict__ qkv1_b,
                             const void* __restrict__ qkv2_w, const void* __restrict__ qkv2_b,
                             const void* __restrict__ pos_w,  const void* __restrict__ pos_b,
                             const void* __restrict__ in1_w,  const void* __restrict__ in1_b,
                             const void* __restrict__ out1_w, const void* __restrict__ out1_b,
                             const void* __restrict__ in2_w,  const void* __restrict__ in2_b,
                             const void* __restrict__ out2_w, const void* __restrict__ out2_b,
                             const int* __restrict__ flag, float* __restrict__ wsW) {
    const int F = *flag;
    const int d = blockIdx.x;
    const void* qw  = d ? qkv2_w : qkv1_w;   // (3,C,C)
    const void* qb  = d ? qkv2_b : qkv1_b;   // (3,C)
    const void* iw  = d ? in2_w  : in1_w;    // (3C,C)
    const void* ib  = d ? in2_b  : in1_b;    // (3C,)
    const void* ow  = d ? out2_w : out1_w;   // (C,C)
    const void* obp = d ? out2_b : out1_b;   // (C,)
    float* o = wsW + d * WB_STRIDE;
    const int tid = threadIdx.x;

    for (int k = 0; k < 4; ++k) {
        const int idx = tid + k * 256;       // 0..1023
        const int t = idx >> 5, i = idx & 31;
        float aq = 0.f, ak = 0.f, av = 0.f;
        #pragma unroll
        for (int u = 0; u < 32; ++u) {
            const float q0 = ldf(qw, u * 32 + t, F);
            const float q1 = ldf(qw, 1024 + u * 32 + t, F);
            const float q2 = ldf(qw, 2048 + u * 32 + t, F);
            aq = fmaf(ldf(iw, i * 32 + u, F),        q0, aq);
            ak = fmaf(ldf(iw, (32 + i) * 32 + u, F), q1, ak);
            av = fmaf(ldf(iw, (64 + i) * 32 + u, F), q2, av);
        }
        o[idx]        = aq;
        o[1024 + idx] = ak;
        o[2048 + idx] = av;
        o[3072 + idx] = ldf(ow, (idx & 31) * 32 + (idx >> 5), F);  // out_w transposed
    }
    if (tid < 32) {
        const int i = tid;
        float aq = 0.f, ak = 0.f, av = 0.f;
        #pragma unroll
        for (int u = 0; u < 32; ++u) {
            aq = fmaf(ldf(qb, u, F),      ldf(iw, i * 32 + u, F),        aq);
            ak = fmaf(ldf(qb, 32 + u, F), ldf(iw, (32 + i) * 32 + u, F), ak);
            av = fmaf(ldf(qb, 64 + u, F), ldf(iw, (64 + i) * 32 + u, F), av);
        }
        o[4096 + i] = aq + ldf(ib, i, F);
        o[4128 + i] = ak + ldf(ib, 32 + i, F);
        o[4160 + i] = av + ldf(ib, 64 + i, F);
        o[4192 + i] = ldf(obp, i, F);
        o[4224 + i] = ldf(ib, 32 + i, F);   // bk raw (masked-slot k)
        o[4256 + i] = ldf(ib, 64 + i, F);   // bv raw (masked-slot v)
    }
    for (int idx = tid; idx < 288; idx += 256) {
        const int s = idx >> 5, i = idx & 31;
        const float sy = (float)c_SY[s], sx = (float)c_SX[s];
        float acc = 0.f;
        #pragma unroll
        for (int j = 0; j < 32; ++j) {
            const float pj = sy * ldf(pos_w, j * 2 + 0, F) + sx * ldf(pos_w, j * 2 + 1, F)
                           + ldf(pos_b, j, F);
            acc = fmaf(pj, ldf(iw, (64 + i) * 32 + j, F), acc);
        }
        o[4288 + idx] = acc;   // posv[s][i] = pos[s] @ wv.T
    }
}

__global__ void build_lut(const int* __restrict__ li_coors, const int* __restrict__ ra_coors,
                          int* __restrict__ lut) {
    const int t = blockIdx.x * 256 + threadIdx.x;
    if (t >= 2 * BB * NN) return;
    const int tensor = t / (BB * NN);
    const int r = t % (BB * NN);
    const int b = r / NN, n = r % NN;
    const int* cc = tensor ? ra_coors : li_coors;
    const int y = cc[(size_t)(b * NN + n) * 2 + 0];
    const int x = cc[(size_t)(b * NN + n) * 2 + 1];
    lut[(size_t)(tensor * BB + b) * HWP + y * WW + x] = n;
}

__launch_bounds__(256)
__global__ void project_kernel(const void* __restrict__ li_feats, const void* __restrict__ ra_feats,
                               const void* __restrict__ li_nw, const void* __restrict__ li_nb,
                               const void* __restrict__ ra_nw, const void* __restrict__ ra_nb,
                               const int* __restrict__ flag, const float* __restrict__ wsW,
                               __hip_bfloat16* __restrict__ qOut, __hip_bfloat16* __restrict__ kOut,
                               __hip_bfloat16* __restrict__ vOut) {
    const int F = *flag;
    const int combo  = blockIdx.x / PBLK;     // 0..7 : tensor*4 + b
    const int blk    = blockIdx.x % PBLK;
    const int tensor = combo >> 2;            // 0 = li, 1 = ra
    const int b      = combo & 3;
    const int qd  = tensor;                   // li queries use dir0 weights, ra -> dir1
    const int kvd = 1 - tensor;               // li is kv for dir1, ra is kv for dir0

    __shared__ float wq[1024], wk[1024], wv[1024];
    __shared__ float bq[32], bk[32], bvv[32], nw[32], nb[32];
    const float* Wq  = wsW + qd  * WB_STRIDE;
    const float* Wkv = wsW + kvd * WB_STRIDE;
    for (int k = threadIdx.x; k < 1024; k += 256) {
        wq[k] = Wq[k];
        wk[k] = Wkv[1024 + k];
        wv[k] = Wkv[2048 + k];
    }
    if (threadIdx.x < 32) {
        bq[threadIdx.x]  = Wq[4096 + threadIdx.x];
        bk[threadIdx.x]  = Wkv[4128 + threadIdx.x];
        bvv[threadIdx.x] = Wkv[4160 + threadIdx.x];
        const void* w  = tensor ? ra_nw : li_nw;
        const void* bb = tensor ? ra_nb : li_nb;
        nw[threadIdx.x] = ldf(w, threadIdx.x, F);
        nb[threadIdx.x] = ldf(bb, threadIdx.x, F);
    }
    __syncthreads();

    const void* feats = tensor ? ra_feats : li_feats;
    const int lane = threadIdx.x & 31;
    const int sub  = threadIdx.x >> 5;   // 0..7

    for (int n0 = blk * 8; n0 < NN; n0 += PBLK * 8) {
        const int n = n0 + sub;
        if (n < NN) {
            const float x = ldf(feats, (b * NN + n) * CC + lane, F);
            float s = x;
            #pragma unroll
            for (int m = 1; m < 32; m <<= 1) s += __shfl_xor(s, m);
            const float mu = s * (1.f / 32.f);
            const float dx = x - mu;
            float s2 = dx * dx;
            #pragma unroll
            for (int m = 1; m < 32; m <<= 1) s2 += __shfl_xor(s2, m);
            const float var = s2 * (1.f / 32.f);
            const float xn = dx * rsqrtf(var + 1e-5f) * nw[lane] + nb[lane];

            float aq = bq[lane], ak = bk[lane], av = bvv[lane];
            #pragma unroll
            for (int t = 0; t < 32; ++t) {
                const float xb = __shfl(xn, t, 32);
                aq = fmaf(wq[t * 32 + lane], xb, aq);
                ak = fmaf(wk[t * 32 + lane], xb, ak);
                av = fmaf(wv[t * 32 + lane], xb, av);
            }
            const size_t off = ((size_t)(tensor * BB + b) * NN + n) * CC + lane;
            qOut[off] = __float2bfloat16(aq);
            kOut[off] = __float2bfloat16(ak);
            vOut[off] = __float2bfloat16(av);
        }
    }
}

__launch_bounds__(256)
__global__ void attn_kernel(const int* __restrict__ li_coors, const int* __restrict__ ra_coors,
                            const float* __restrict__ wsW, const int* __restrict__ lut,
                            const __hip_bfloat16* __restrict__ qArr, const __hip_bfloat16* __restrict__ kArr,
                            const __hip_bfloat16* __restrict__ vArr, __hip_bfloat16* __restrict__ resArr) {
    const int combo = blockIdx.x / ABLK;   // dir*4 + b
    const int blk   = blockIdx.x % ABLK;
    const int d = combo >> 2;
    const int b = combo & 3;
    const int qt = d;          // dir0: q = li(0); dir1: q = ra(1)
    const int kt = 1 - d;

    __shared__ float wo[1024], ob[32], bkr[32], bvr[32], pv[288];
    const float* Wd = wsW + d * WB_STRIDE;
    for (int k = threadIdx.x; k < 1024; k += 256) wo[k] = Wd[3072 + k];
    if (threadIdx.x < 32) {
        ob[threadIdx.x]  = Wd[4192 + threadIdx.x];
        bkr[threadIdx.x] = Wd[4224 + threadIdx.x];
        bvr[threadIdx.x] = Wd[4256 + threadIdx.x];
    }
    for (int k = threadIdx.x; k < 288; k += 256) pv[k] = Wd[4288 + k];
    __syncthreads();

    const int* qc = qt ? ra_coors : li_coors;
    const int* lutk = lut + (size_t)(kt * BB + b) * HWP;
    const __hip_bfloat16* kk = kArr + (size_t)(kt * BB + b) * NN * CC;
    const __hip_bfloat16* vv = vArr + (size_t)(kt * BB + b) * NN * CC;
    const __hip_bfloat16* qq = qArr + (size_t)(qt * BB + b) * NN * CC;
    __hip_bfloat16* res = resArr + (size_t)(d * BB + b) * NN * CC;

    const int lane = threadIdx.x & 31;
    const int sub  = threadIdx.x >> 5;

    for (int n0 = blk * 8; n0 < NN; n0 += ABLK * 8) {
        const int n = n0 + sub;
        if (n >= NN) continue;
        const float qv = bf(qq[(size_t)n * CC + lane]);   // read BEFORE res (aliased) write
        const int y = qc[(size_t)(b * NN + n) * 2 + 0];
        const int x = qc[(size_t)(b * NN + n) * 2 + 1];

        float sc[9], vr[9];
        #pragma unroll
        for (int s = 0; s < 9; ++s) {
            const int ny = y + c_SY[s], nx = x + c_SX[s];
            int idx = -1;
            if (ny >= 0 && ny < HH && nx >= 0 && nx < WW) idx = lutk[ny * WW + nx];
            float kc, vc;
            if (idx >= 0) {
                kc = bf(kk[(size_t)idx * CC + lane]);
                vc = bf(vv[(size_t)idx * CC + lane]) + pv[s * 32 + lane];
            } else {
                kc = bkr[lane];
                vc = bvr[lane];
            }
            vr[s] = vc;
            float p = qv * kc;
            p += __shfl_xor(p, 1);
            p += __shfl_xor(p, 2);
            p += __shfl_xor(p, 4);
            p += __shfl_xor(p, 8);   // sum over 16-lane head group
            sc[s] = p * 0.25f;       // 1/sqrt(16)
        }
        float m = sc[0];
        #pragma unroll
        for (int s = 1; s < 9; ++s) m = fmaxf(m, sc[s]);
        float den = 0.f, oc = 0.f;
        #pragma unroll
        for (int s = 0; s < 9; ++s) {
            const float e = __expf(sc[s] - m);
            den += e;
            oc = fmaf(e, vr[s], oc);
        }
        oc /= den;
        // out = o @ out_w.T + out_b
        float acc = ob[lane];
        #pragma unroll
        for (int j = 0; j < 32; ++j) {
            const float oj = __shfl(oc, j, 32);
            acc = fmaf(wo[j * 32 + lane], oj, acc);
        }
        res[(size_t)n * CC + lane] = __float2bfloat16(acc);
    }
}

__launch_bounds__(256)
__global__ void canvas_kernel(const int* __restrict__ lut, const __hip_bfloat16* __restrict__ resArr,
                              const int* __restrict__ flag, void* __restrict__ out) {
    const int F = *flag;
    const int tile = blockIdx.x % (HWP / 64);
    const int rem  = blockIdx.x / (HWP / 64);
    const int b = rem & 3;
    const int d = rem >> 2;
    const int* lutq = lut + (size_t)(d * BB + b) * HWP + (size_t)tile * 64;
    __shared__ int ls[64];
    if (threadIdx.x < 64) ls[threadIdx.x] = lutq[threadIdx.x];
    __syncthreads();
    const __hip_bfloat16* res = resArr + (size_t)(d * BB + b) * NN * CC;
    const size_t obase = (size_t)(d * BB + b) * CC * HWP + (size_t)tile * 64;
    const int px = threadIdx.x & 63;
    const int c0 = threadIdx.x >> 6;   // 0..3
    const int idx = ls[px];
    if (F) {
        float* ob = (float*)out + obase;
        #pragma unroll
        for (int c = c0; c < CC; c += 4) {
            float v = 0.f;
            if (idx >= 0) v = bf(res[(size_t)idx * CC + c]);
            ob[(size_t)c * HWP + px] = v;
        }
    } else {
        __hip_bfloat16* ob = (__hip_bfloat16*)out + obase;
        #pragma unroll
        for (int c = c0; c < CC; c += 4) {
            float v = 0.f;
            if (idx >= 0) v = bf(res[(size_t)idx * CC + c]);
            ob[(size_t)c * HWP + px] = __float2bfloat16(v);
        }
    }
}

extern "C" void kernel_launch(void* const* d_in, const int* in_sizes, int n_in,
                              void* d_out, int out_size, void* d_ws, size_t ws_size,
                              hipStream_t stream) {
    (void)in_sizes; (void)n_in; (void)out_size; (void)ws_size;
    const void* li_feats = d_in[0];
    const void* ra_feats = d_in[1];
    const int* li_coors = (const int*)d_in[2];
    const int* ra_coors = (const int*)d_in[3];
    const void* li_nw = d_in[4];
    const void* li_nb = d_in[5];
    const void* ra_nw = d_in[6];
    const void* ra_nb = d_in[7];

    char* ws = (char*)d_ws;
    int*   flag = (int*)ws;                                   // 4 B
    float* wsW  = (float*)(ws + 512);                         // 36,864 B -> ends 37,376
    int*   lut  = (int*)(ws + 40960);                         // 6,422,528 B -> ends 6,463,488
    __hip_bfloat16* qArr = (__hip_bfloat16*)(ws + 6463488);   // 10,240,000 B each
    __hip_bfloat16* kArr = (__hip_bfloat16*)(ws + 16703488);
    __hip_bfloat16* vArr = (__hip_bfloat16*)(ws + 26943488);  // ends 37,183,488 (~35.5 MB)
    __hip_bfloat16* rArr = qArr;  // aliased: q[n] read only by the thread that writes res[n]

    sniff_kernel<<<1, 256, 0, stream>>>(li_feats, flag);
    prep_weights<<<2, 256, 0, stream>>>(d_in[8], d_in[9], d_in[10], d_in[11], d_in[12], d_in[13],
                                        d_in[14], d_in[15], d_in[16], d_in[17],
                                        d_in[18], d_in[19], d_in[20], d_in[21], flag, wsW);
    hipMemsetAsync(lut, 0xFF, (size_t)2 * BB * HWP * sizeof(int), stream);
    build_lut<<<(2 * BB * NN + 255) / 256, 256, 0, stream>>>(li_coors, ra_coors, lut);
    project_kernel<<<8 * PBLK, 256, 0, stream>>>(li_feats, ra_feats, li_nw, li_nb, ra_nw, ra_nb,
                                                 flag, wsW, qArr, kArr, vArr);
    attn_kernel<<<8 * ABLK, 256, 0, stream>>>(li_coors, ra_coors, wsW, lut, qArr, kArr, vArr, rArr);
    canvas_kernel<<<2 * BB * (HWP / 64), 256, 0, stream>>>(lut, rArr, flag, d_out);
}

// Round 3
// 439.413 us; speedup vs baseline: 1.3499x; 1.3499x over previous
//
#include <hip/hip_runtime.h>
#include <hip/hip_bf16.h>

#define HH 448
#define WW 448
#define HWP (HH*WW)
#define CC 32
#define NN 20000
#define BB 4
#define PBLK 256
#define ABLK 256

// SHIFTS = [[0,0],[-1,0],[1,0],[0,1],[-1,1],[1,1],[0,-1],[-1,-1],[1,-1]]
__constant__ int c_SY[9] = {0,-1,1,0,-1,1,0,-1,1};
__constant__ int c_SX[9] = {0,0,0,1,1,1,-1,-1,-1};

// Per-direction fused weight block layout (floats), stride 4608:
// [0:1024]  WqT : WqT[t*32+i] = (wq@qkv_w0)[i][t]
// [1024:2048] WkT, [2048:3072] WvT
// [3072:4096] WoT : WoT[j*32+c] = out_w[c][j]
// [4096] bq_f(32) [4128] bk_f(32) [4160] bv_f(32) [4192] out_b(32)
// [4224] bk_raw(32) [4256] bv_raw(32) [4288:4576] posv(9x32)
#define WB_STRIDE 4608

static __device__ __forceinline__ float bf(const __hip_bfloat16 v) {
    return __bfloat162float(v);
}

// dtype-agnostic load: isf32 ? float[i] : bf16[i]
static __device__ __forceinline__ float ldf(const void* p, int i, int isf32) {
    if (isf32) return ((const float*)p)[i];
    return __bfloat162float(((const __hip_bfloat16*)p)[i]);
}

// Detect whether float tensors are stored as f32 or bf16.
__global__ void sniff_kernel(const void* __restrict__ feats, int* __restrict__ flag) {
    __shared__ int cnt[256];
    const unsigned short u = ((const unsigned short*)feats)[threadIdx.x * 2];
    const int e = (u >> 7) & 0xFF;
    cnt[threadIdx.x] = (u == 0 || (e >= 97 && e <= 157)) ? 1 : 0;
    __syncthreads();
    for (int s = 128; s > 0; s >>= 1) {
        if (threadIdx.x < s) cnt[threadIdx.x] += cnt[threadIdx.x + s];
        __syncthreads();
    }
    if (threadIdx.x == 0) *flag = (cnt[0] >= 192) ? 0 : 1;   // 1 => f32
}

// R2: LDS-staged weight prep. Old version issued ~770 serialized scalar global
// loads per thread from 2 blocks -> ~175 us latency-bound. Stage everything
// into LDS with coalesced loads, compute from LDS (iw/ow padded to stride 33:
// lane-indexed row access at stride 32 would be a 32-way bank conflict).
__launch_bounds__(256)
__global__ void prep_weights(const void* __restrict__ qkv1_w, const void* __restrict__ qkv1_b,
                             const void* __restrict__ qkv2_w, const void* __restrict__ qkv2_b,
                             const void* __restrict__ pos_w,  const void* __restrict__ pos_b,
                             const void* __restrict__ in1_w,  const void* __restrict__ in1_b,
                             const void* __restrict__ out1_w, const void* __restrict__ out1_b,
                             const void* __restrict__ in2_w,  const void* __restrict__ in2_b,
                             const void* __restrict__ out2_w, const void* __restrict__ out2_b,
                             const int* __restrict__ flag, float* __restrict__ wsW) {
    const int F = *flag;
    const int d = blockIdx.x;
    const void* qw  = d ? qkv2_w : qkv1_w;   // (3,C,C)
    const void* qb  = d ? qkv2_b : qkv1_b;   // (3,C)
    const void* iw  = d ? in2_w  : in1_w;    // (3C,C)
    const void* ib  = d ? in2_b  : in1_b;    // (3C,)
    const void* ow  = d ? out2_w : out1_w;   // (C,C)
    const void* obp = d ? out2_b : out1_b;   // (C,)
    float* o = wsW + d * WB_STRIDE;
    const int tid = threadIdx.x;

    __shared__ float s_qw[3072];
    __shared__ float s_iw[96 * 33];
    __shared__ float s_ow[32 * 33];
    __shared__ float s_qb[96], s_ib[96], s_obp[32], s_pw[64], s_pb[32];

    if (F) {
        const float* fqw = (const float*)qw;  const float* fiw = (const float*)iw;
        const float* fow = (const float*)ow;  const float* fqb = (const float*)qb;
        const float* fib = (const float*)ib;  const float* fob = (const float*)obp;
        const float* fpw = (const float*)pos_w; const float* fpb = (const float*)pos_b;
        for (int i = tid; i < 3072; i += 256) s_qw[i] = fqw[i];
        for (int i = tid; i < 3072; i += 256) s_iw[(i >> 5) * 33 + (i & 31)] = fiw[i];
        for (int i = tid; i < 1024; i += 256) s_ow[(i >> 5) * 33 + (i & 31)] = fow[i];
        if (tid < 96) { s_qb[tid] = fqb[tid]; s_ib[tid] = fib[tid]; }
        if (tid < 64) s_pw[tid] = fpw[tid];
        if (tid < 32) { s_obp[tid] = fob[tid]; s_pb[tid] = fpb[tid]; }
    } else {
        const __hip_bfloat16* hqw = (const __hip_bfloat16*)qw;  const __hip_bfloat16* hiw = (const __hip_bfloat16*)iw;
        const __hip_bfloat16* how = (const __hip_bfloat16*)ow;  const __hip_bfloat16* hqb = (const __hip_bfloat16*)qb;
        const __hip_bfloat16* hib = (const __hip_bfloat16*)ib;  const __hip_bfloat16* hob = (const __hip_bfloat16*)obp;
        const __hip_bfloat16* hpw = (const __hip_bfloat16*)pos_w; const __hip_bfloat16* hpb = (const __hip_bfloat16*)pos_b;
        for (int i = tid; i < 3072; i += 256) s_qw[i] = bf(hqw[i]);
        for (int i = tid; i < 3072; i += 256) s_iw[(i >> 5) * 33 + (i & 31)] = bf(hiw[i]);
        for (int i = tid; i < 1024; i += 256) s_ow[(i >> 5) * 33 + (i & 31)] = bf(how[i]);
        if (tid < 96) { s_qb[tid] = bf(hqb[tid]); s_ib[tid] = bf(hib[tid]); }
        if (tid < 64) s_pw[tid] = bf(hpw[tid]);
        if (tid < 32) { s_obp[tid] = bf(hob[tid]); s_pb[tid] = bf(hpb[tid]); }
    }
    __syncthreads();

    for (int k = 0; k < 4; ++k) {
        const int idx = tid + k * 256;       // 0..1023
        const int t = idx >> 5, i = idx & 31;
        float aq = 0.f, ak = 0.f, av = 0.f;
        #pragma unroll
        for (int u = 0; u < 32; ++u) {
            const float q0 = s_qw[u * 32 + t];          // lane-uniform broadcast
            const float q1 = s_qw[1024 + u * 32 + t];
            const float q2 = s_qw[2048 + u * 32 + t];
            aq = fmaf(s_iw[i * 33 + u],        q0, aq); // stride-33: conflict-free
            ak = fmaf(s_iw[(32 + i) * 33 + u], q1, ak);
            av = fmaf(s_iw[(64 + i) * 33 + u], q2, av);
        }
        o[idx]        = aq;
        o[1024 + idx] = ak;
        o[2048 + idx] = av;
        o[3072 + idx] = s_ow[i * 33 + t];   // out_w transposed
    }
    if (tid < 32) {
        const int i = tid;
        float aq = 0.f, ak = 0.f, av = 0.f;
        #pragma unroll
        for (int u = 0; u < 32; ++u) {
            aq = fmaf(s_qb[u],      s_iw[i * 33 + u],        aq);
            ak = fmaf(s_qb[32 + u], s_iw[(32 + i) * 33 + u], ak);
            av = fmaf(s_qb[64 + u], s_iw[(64 + i) * 33 + u], av);
        }
        o[4096 + i] = aq + s_ib[i];
        o[4128 + i] = ak + s_ib[32 + i];
        o[4160 + i] = av + s_ib[64 + i];
        o[4192 + i] = s_obp[i];
        o[4224 + i] = s_ib[32 + i];   // bk raw (masked-slot k)
        o[4256 + i] = s_ib[64 + i];   // bv raw (masked-slot v)
    }
    for (int idx = tid; idx < 288; idx += 256) {
        const int s = idx >> 5, i = idx & 31;
        const float sy = (float)c_SY[s], sx = (float)c_SX[s];
        float acc = 0.f;
        #pragma unroll
        for (int j = 0; j < 32; ++j) {
            const float pj = sy * s_pw[j * 2 + 0] + sx * s_pw[j * 2 + 1] + s_pb[j];
            acc = fmaf(pj, s_iw[(64 + i) * 33 + j], acc);
        }
        o[4288 + idx] = acc;   // posv[s][i] = pos[s] @ wv.T
    }
}

__global__ void build_lut(const int* __restrict__ li_coors, const int* __restrict__ ra_coors,
                          int* __restrict__ lut) {
    const int t = blockIdx.x * 256 + threadIdx.x;
    if (t >= 2 * BB * NN) return;
    const int tensor = t / (BB * NN);
    const int r = t % (BB * NN);
    const int b = r / NN, n = r % NN;
    const int* cc = tensor ? ra_coors : li_coors;
    const int y = cc[(size_t)(b * NN + n) * 2 + 0];
    const int x = cc[(size_t)(b * NN + n) * 2 + 1];
    lut[(size_t)(tensor * BB + b) * HWP + y * WW + x] = n;
}

__launch_bounds__(256)
__global__ void project_kernel(const void* __restrict__ li_feats, const void* __restrict__ ra_feats,
                               const void* __restrict__ li_nw, const void* __restrict__ li_nb,
                               const void* __restrict__ ra_nw, const void* __restrict__ ra_nb,
                               const int* __restrict__ flag, const float* __restrict__ wsW,
                               __hip_bfloat16* __restrict__ qOut, __hip_bfloat16* __restrict__ kOut,
                               __hip_bfloat16* __restrict__ vOut) {
    const int F = *flag;
    const int combo  = blockIdx.x / PBLK;     // 0..7 : tensor*4 + b
    const int blk    = blockIdx.x % PBLK;
    const int tensor = combo >> 2;            // 0 = li, 1 = ra
    const int b      = combo & 3;
    const int qd  = tensor;                   // li queries use dir0 weights, ra -> dir1
    const int kvd = 1 - tensor;               // li is kv for dir1, ra is kv for dir0

    __shared__ float wq[1024], wk[1024], wv[1024];
    __shared__ float bq[32], bk[32], bvv[32], nw[32], nb[32];
    const float* Wq  = wsW + qd  * WB_STRIDE;
    const float* Wkv = wsW + kvd * WB_STRIDE;
    for (int k = threadIdx.x; k < 1024; k += 256) {
        wq[k] = Wq[k];
        wk[k] = Wkv[1024 + k];
        wv[k] = Wkv[2048 + k];
    }
    if (threadIdx.x < 32) {
        bq[threadIdx.x]  = Wq[4096 + threadIdx.x];
        bk[threadIdx.x]  = Wkv[4128 + threadIdx.x];
        bvv[threadIdx.x] = Wkv[4160 + threadIdx.x];
        const void* w  = tensor ? ra_nw : li_nw;
        const void* bb = tensor ? ra_nb : li_nb;
        nw[threadIdx.x] = ldf(w, threadIdx.x, F);
        nb[threadIdx.x] = ldf(bb, threadIdx.x, F);
    }
    __syncthreads();

    const void* feats = tensor ? ra_feats : li_feats;
    const int lane = threadIdx.x & 31;
    const int sub  = threadIdx.x >> 5;   // 0..7

    for (int n0 = blk * 8; n0 < NN; n0 += PBLK * 8) {
        const int n = n0 + sub;
        if (n < NN) {
            const float x = ldf(feats, (b * NN + n) * CC + lane, F);
            float s = x;
            #pragma unroll
            for (int m = 1; m < 32; m <<= 1) s += __shfl_xor(s, m);
            const float mu = s * (1.f / 32.f);
            const float dx = x - mu;
            float s2 = dx * dx;
            #pragma unroll
            for (int m = 1; m < 32; m <<= 1) s2 += __shfl_xor(s2, m);
            const float var = s2 * (1.f / 32.f);
            const float xn = dx * rsqrtf(var + 1e-5f) * nw[lane] + nb[lane];

            float aq = bq[lane], ak = bk[lane], av = bvv[lane];
            #pragma unroll
            for (int t = 0; t < 32; ++t) {
                const float xb = __shfl(xn, t, 32);
                aq = fmaf(wq[t * 32 + lane], xb, aq);
                ak = fmaf(wk[t * 32 + lane], xb, ak);
                av = fmaf(wv[t * 32 + lane], xb, av);
            }
            const size_t off = ((size_t)(tensor * BB + b) * NN + n) * CC + lane;
            qOut[off] = __float2bfloat16(aq);
            kOut[off] = __float2bfloat16(ak);
            vOut[off] = __float2bfloat16(av);
        }
    }
}

__launch_bounds__(256)
__global__ void attn_kernel(const int* __restrict__ li_coors, const int* __restrict__ ra_coors,
                            const float* __restrict__ wsW, const int* __restrict__ lut,
                            const __hip_bfloat16* __restrict__ qArr, const __hip_bfloat16* __restrict__ kArr,
                            const __hip_bfloat16* __restrict__ vArr, __hip_bfloat16* __restrict__ resArr) {
    const int combo = blockIdx.x / ABLK;   // dir*4 + b
    const int blk   = blockIdx.x % ABLK;
    const int d = combo >> 2;
    const int b = combo & 3;
    const int qt = d;          // dir0: q = li(0); dir1: q = ra(1)
    const int kt = 1 - d;

    __shared__ float wo[1024], ob[32], bkr[32], bvr[32], pv[288];
    const float* Wd = wsW + d * WB_STRIDE;
    for (int k = threadIdx.x; k < 1024; k += 256) wo[k] = Wd[3072 + k];
    if (threadIdx.x < 32) {
        ob[threadIdx.x]  = Wd[4192 + threadIdx.x];
        bkr[threadIdx.x] = Wd[4224 + threadIdx.x];
        bvr[threadIdx.x] = Wd[4256 + threadIdx.x];
    }
    for (int k = threadIdx.x; k < 288; k += 256) pv[k] = Wd[4288 + k];
    __syncthreads();

    const int* qc = qt ? ra_coors : li_coors;
    const int* lutk = lut + (size_t)(kt * BB + b) * HWP;
    const __hip_bfloat16* kk = kArr + (size_t)(kt * BB + b) * NN * CC;
    const __hip_bfloat16* vv = vArr + (size_t)(kt * BB + b) * NN * CC;
    const __hip_bfloat16* qq = qArr + (size_t)(qt * BB + b) * NN * CC;
    __hip_bfloat16* res = resArr + (size_t)(d * BB + b) * NN * CC;

    const int lane = threadIdx.x & 31;
    const int sub  = threadIdx.x >> 5;

    for (int n0 = blk * 8; n0 < NN; n0 += ABLK * 8) {
        const int n = n0 + sub;
        if (n >= NN) continue;
        const float qv = bf(qq[(size_t)n * CC + lane]);   // read BEFORE res (aliased) write
        const int y = qc[(size_t)(b * NN + n) * 2 + 0];
        const int x = qc[(size_t)(b * NN + n) * 2 + 1];

        float sc[9], vr[9];
        #pragma unroll
        for (int s = 0; s < 9; ++s) {
            const int ny = y + c_SY[s], nx = x + c_SX[s];
            int idx = -1;
            if (ny >= 0 && ny < HH && nx >= 0 && nx < WW) idx = lutk[ny * WW + nx];
            float kc, vc;
            if (idx >= 0) {
                kc = bf(kk[(size_t)idx * CC + lane]);
                vc = bf(vv[(size_t)idx * CC + lane]) + pv[s * 32 + lane];
            } else {
                kc = bkr[lane];
                vc = bvr[lane];
            }
            vr[s] = vc;
            float p = qv * kc;
            p += __shfl_xor(p, 1);
            p += __shfl_xor(p, 2);
            p += __shfl_xor(p, 4);
            p += __shfl_xor(p, 8);   // sum over 16-lane head group
            sc[s] = p * 0.25f;       // 1/sqrt(16)
        }
        float m = sc[0];
        #pragma unroll
        for (int s = 1; s < 9; ++s) m = fmaxf(m, sc[s]);
        float den = 0.f, oc = 0.f;
        #pragma unroll
        for (int s = 0; s < 9; ++s) {
            const float e = __expf(sc[s] - m);
            den += e;
            oc = fmaf(e, vr[s], oc);
        }
        oc /= den;
        // out = o @ out_w.T + out_b
        float acc = ob[lane];
        #pragma unroll
        for (int j = 0; j < 32; ++j) {
            const float oj = __shfl(oc, j, 32);
            acc = fmaf(wo[j * 32 + lane], oj, acc);
        }
        res[(size_t)n * CC + lane] = __float2bfloat16(acc);
    }
}

__launch_bounds__(256)
__global__ void canvas_kernel(const int* __restrict__ lut, const __hip_bfloat16* __restrict__ resArr,
                              const int* __restrict__ flag, void* __restrict__ out) {
    const int F = *flag;
    const int tile = blockIdx.x % (HWP / 64);
    const int rem  = blockIdx.x / (HWP / 64);
    const int b = rem & 3;
    const int d = rem >> 2;
    const int* lutq = lut + (size_t)(d * BB + b) * HWP + (size_t)tile * 64;
    __shared__ int ls[64];
    if (threadIdx.x < 64) ls[threadIdx.x] = lutq[threadIdx.x];
    __syncthreads();
    const __hip_bfloat16* res = resArr + (size_t)(d * BB + b) * NN * CC;
    const size_t obase = (size_t)(d * BB + b) * CC * HWP + (size_t)tile * 64;
    const int px = threadIdx.x & 63;
    const int c0 = threadIdx.x >> 6;   // 0..3
    const int idx = ls[px];
    if (F) {
        float* ob = (float*)out + obase;
        #pragma unroll
        for (int c = c0; c < CC; c += 4) {
            float v = 0.f;
            if (idx >= 0) v = bf(res[(size_t)idx * CC + c]);
            ob[(size_t)c * HWP + px] = v;
        }
    } else {
        __hip_bfloat16* ob = (__hip_bfloat16*)out + obase;
        #pragma unroll
        for (int c = c0; c < CC; c += 4) {
            float v = 0.f;
            if (idx >= 0) v = bf(res[(size_t)idx * CC + c]);
            ob[(size_t)c * HWP + px] = __float2bfloat16(v);
        }
    }
}

extern "C" void kernel_launch(void* const* d_in, const int* in_sizes, int n_in,
                              void* d_out, int out_size, void* d_ws, size_t ws_size,
                              hipStream_t stream) {
    (void)in_sizes; (void)n_in; (void)out_size; (void)ws_size;
    const void* li_feats = d_in[0];
    const void* ra_feats = d_in[1];
    const int* li_coors = (const int*)d_in[2];
    const int* ra_coors = (const int*)d_in[3];
    const void* li_nw = d_in[4];
    const void* li_nb = d_in[5];
    const void* ra_nw = d_in[6];
    const void* ra_nb = d_in[7];

    char* ws = (char*)d_ws;
    int*   flag = (int*)ws;                                   // 4 B
    float* wsW  = (float*)(ws + 512);                         // 36,864 B -> ends 37,376
    int*   lut  = (int*)(ws + 40960);                         // 6,422,528 B -> ends 6,463,488
    __hip_bfloat16* qArr = (__hip_bfloat16*)(ws + 6463488);   // 10,240,000 B each
    __hip_bfloat16* kArr = (__hip_bfloat16*)(ws + 16703488);
    __hip_bfloat16* vArr = (__hip_bfloat16*)(ws + 26943488);  // ends 37,183,488 (~35.5 MB)
    __hip_bfloat16* rArr = qArr;  // aliased: q[n] read only by the thread that writes res[n]

    sniff_kernel<<<1, 256, 0, stream>>>(li_feats, flag);
    prep_weights<<<2, 256, 0, stream>>>(d_in[8], d_in[9], d_in[10], d_in[11], d_in[12], d_in[13],
                                        d_in[14], d_in[15], d_in[16], d_in[17],
                                        d_in[18], d_in[19], d_in[20], d_in[21], flag, wsW);
    hipMemsetAsync(lut, 0xFF, (size_t)2 * BB * HWP * sizeof(int), stream);
    build_lut<<<(2 * BB * NN + 255) / 256, 256, 0, stream>>>(li_coors, ra_coors, lut);
    project_kernel<<<8 * PBLK, 256, 0, stream>>>(li_feats, ra_feats, li_nw, li_nb, ra_nw, ra_nb,
                                                 flag, wsW, qArr, kArr, vArr);
    attn_kernel<<<8 * ABLK, 256, 0, stream>>>(li_coors, ra_coors, wsW, lut, qArr, kArr, vArr, rArr);
    canvas_kernel<<<2 * BB * (HWP / 64), 256, 0, stream>>>(lut, rArr, flag, d_out);
}

// Round 4
// 433.304 us; speedup vs baseline: 1.3689x; 1.0141x over previous
//
#include <hip/hip_runtime.h>
#include <hip/hip_bf16.h>

#define HH 448
#define WW 448
#define HWP (HH*WW)
#define CC 32
#define NN 20000
#define BB 4
#define PBLK 512
#define ABLK 512

// SHIFTS = [[0,0],[-1,0],[1,0],[0,1],[-1,1],[1,1],[0,-1],[-1,-1],[1,-1]]
__constant__ int c_SY[9] = {0,-1,1,0,-1,1,0,-1,1};
__constant__ int c_SX[9] = {0,0,0,1,1,1,-1,-1,-1};

// Per-direction fused weight block layout (floats), stride 4608:
// [0:1024]  WqT : WqT[t*32+i] = (wq@qkv_w0)[i][t]
// [1024:2048] WkT, [2048:3072] WvT
// [3072:4096] WoT : WoT[j*32+c] = out_w[c][j]
// [4096] bq_f(32) [4128] bk_f(32) [4160] bv_f(32) [4192] out_b(32)
// [4224] bk_raw(32) [4256] bv_raw(32) [4288:4576] posv(9x32)
#define WB_STRIDE 4608

static __device__ __forceinline__ float bf(const __hip_bfloat16 v) {
    return __bfloat162float(v);
}

// dtype-agnostic load: isf32 ? float[i] : bf16[i]
static __device__ __forceinline__ float ldf(const void* p, int i, int isf32) {
    if (isf32) return ((const float*)p)[i];
    return __bfloat162float(((const __hip_bfloat16*)p)[i]);
}

// R4: sniff folded into prep_weights (each block votes locally; block 0
// publishes flag for downstream kernels). Saves one dispatch + stall.
__launch_bounds__(256)
__global__ void prep_weights(const void* __restrict__ qkv1_w, const void* __restrict__ qkv1_b,
                             const void* __restrict__ qkv2_w, const void* __restrict__ qkv2_b,
                             const void* __restrict__ pos_w,  const void* __restrict__ pos_b,
                             const void* __restrict__ in1_w,  const void* __restrict__ in1_b,
                             const void* __restrict__ out1_w, const void* __restrict__ out1_b,
                             const void* __restrict__ in2_w,  const void* __restrict__ in2_b,
                             const void* __restrict__ out2_w, const void* __restrict__ out2_b,
                             const void* __restrict__ li_feats,
                             int* __restrict__ flag, float* __restrict__ wsW) {
    const int tid = threadIdx.x;
    __shared__ int cnt[256];
    {
        // dtype sniff: f32 data seen as u16 pairs -> even words are mantissa
        // low-halves (~23% "sane" exponent); real bf16 N(0,1) -> ~100%.
        const unsigned short u = ((const unsigned short*)li_feats)[tid * 2];
        const int e = (u >> 7) & 0xFF;
        cnt[tid] = (u == 0 || (e >= 97 && e <= 157)) ? 1 : 0;
    }
    __syncthreads();
    for (int s = 128; s > 0; s >>= 1) {
        if (tid < s) cnt[tid] += cnt[tid + s];
        __syncthreads();
    }
    const int F = (cnt[0] >= 192) ? 0 : 1;   // 1 => f32
    if (blockIdx.x == 0 && tid == 0) *flag = F;

    const int d = blockIdx.x;
    const void* qw  = d ? qkv2_w : qkv1_w;   // (3,C,C)
    const void* qb  = d ? qkv2_b : qkv1_b;   // (3,C)
    const void* iw  = d ? in2_w  : in1_w;    // (3C,C)
    const void* ib  = d ? in2_b  : in1_b;    // (3C,)
    const void* ow  = d ? out2_w : out1_w;   // (C,C)
    const void* obp = d ? out2_b : out1_b;   // (C,)
    float* o = wsW + d * WB_STRIDE;

    __shared__ float s_qw[3072];
    __shared__ float s_iw[96 * 33];   // stride-33: lane-row access conflict-free
    __shared__ float s_ow[32 * 33];
    __shared__ float s_qb[96], s_ib[96], s_obp[32], s_pw[64], s_pb[32];

    if (F) {
        const float* fqw = (const float*)qw;  const float* fiw = (const float*)iw;
        const float* fow = (const float*)ow;  const float* fqb = (const float*)qb;
        const float* fib = (const float*)ib;  const float* fob = (const float*)obp;
        const float* fpw = (const float*)pos_w; const float* fpb = (const float*)pos_b;
        for (int i = tid; i < 3072; i += 256) s_qw[i] = fqw[i];
        for (int i = tid; i < 3072; i += 256) s_iw[(i >> 5) * 33 + (i & 31)] = fiw[i];
        for (int i = tid; i < 1024; i += 256) s_ow[(i >> 5) * 33 + (i & 31)] = fow[i];
        if (tid < 96) { s_qb[tid] = fqb[tid]; s_ib[tid] = fib[tid]; }
        if (tid < 64) s_pw[tid] = fpw[tid];
        if (tid < 32) { s_obp[tid] = fob[tid]; s_pb[tid] = fpb[tid]; }
    } else {
        const __hip_bfloat16* hqw = (const __hip_bfloat16*)qw;  const __hip_bfloat16* hiw = (const __hip_bfloat16*)iw;
        const __hip_bfloat16* how = (const __hip_bfloat16*)ow;  const __hip_bfloat16* hqb = (const __hip_bfloat16*)qb;
        const __hip_bfloat16* hib = (const __hip_bfloat16*)ib;  const __hip_bfloat16* hob = (const __hip_bfloat16*)obp;
        const __hip_bfloat16* hpw = (const __hip_bfloat16*)pos_w; const __hip_bfloat16* hpb = (const __hip_bfloat16*)pos_b;
        for (int i = tid; i < 3072; i += 256) s_qw[i] = bf(hqw[i]);
        for (int i = tid; i < 3072; i += 256) s_iw[(i >> 5) * 33 + (i & 31)] = bf(hiw[i]);
        for (int i = tid; i < 1024; i += 256) s_ow[(i >> 5) * 33 + (i & 31)] = bf(how[i]);
        if (tid < 96) { s_qb[tid] = bf(hqb[tid]); s_ib[tid] = bf(hib[tid]); }
        if (tid < 64) s_pw[tid] = bf(hpw[tid]);
        if (tid < 32) { s_obp[tid] = bf(hob[tid]); s_pb[tid] = bf(hpb[tid]); }
    }
    __syncthreads();

    for (int k = 0; k < 4; ++k) {
        const int idx = tid + k * 256;       // 0..1023
        const int t = idx >> 5, i = idx & 31;
        float aq = 0.f, ak = 0.f, av = 0.f;
        #pragma unroll
        for (int u = 0; u < 32; ++u) {
            const float q0 = s_qw[u * 32 + t];          // lane-uniform broadcast
            const float q1 = s_qw[1024 + u * 32 + t];
            const float q2 = s_qw[2048 + u * 32 + t];
            aq = fmaf(s_iw[i * 33 + u],        q0, aq);
            ak = fmaf(s_iw[(32 + i) * 33 + u], q1, ak);
            av = fmaf(s_iw[(64 + i) * 33 + u], q2, av);
        }
        o[idx]        = aq;
        o[1024 + idx] = ak;
        o[2048 + idx] = av;
        o[3072 + idx] = s_ow[i * 33 + t];   // out_w transposed
    }
    if (tid < 32) {
        const int i = tid;
        float aq = 0.f, ak = 0.f, av = 0.f;
        #pragma unroll
        for (int u = 0; u < 32; ++u) {
            aq = fmaf(s_qb[u],      s_iw[i * 33 + u],        aq);
            ak = fmaf(s_qb[32 + u], s_iw[(32 + i) * 33 + u], ak);
            av = fmaf(s_qb[64 + u], s_iw[(64 + i) * 33 + u], av);
        }
        o[4096 + i] = aq + s_ib[i];
        o[4128 + i] = ak + s_ib[32 + i];
        o[4160 + i] = av + s_ib[64 + i];
        o[4192 + i] = s_obp[i];
        o[4224 + i] = s_ib[32 + i];   // bk raw (masked-slot k)
        o[4256 + i] = s_ib[64 + i];   // bv raw (masked-slot v)
    }
    for (int idx = tid; idx < 288; idx += 256) {
        const int s = idx >> 5, i = idx & 31;
        const float sy = (float)c_SY[s], sx = (float)c_SX[s];
        float acc = 0.f;
        #pragma unroll
        for (int j = 0; j < 32; ++j) {
            const float pj = sy * s_pw[j * 2 + 0] + sx * s_pw[j * 2 + 1] + s_pb[j];
            acc = fmaf(pj, s_iw[(64 + i) * 33 + j], acc);
        }
        o[4288 + idx] = acc;   // posv[s][i] = pos[s] @ wv.T
    }
}

__global__ void build_lut(const int* __restrict__ li_coors, const int* __restrict__ ra_coors,
                          int* __restrict__ lut) {
    const int t = blockIdx.x * 256 + threadIdx.x;
    if (t >= 2 * BB * NN) return;
    const int tensor = t / (BB * NN);
    const int r = t % (BB * NN);
    const int b = r / NN, n = r % NN;
    const int* cc = tensor ? ra_coors : li_coors;
    const int y = cc[(size_t)(b * NN + n) * 2 + 0];
    const int x = cc[(size_t)(b * NN + n) * 2 + 1];
    lut[(size_t)(tensor * BB + b) * HWP + y * WW + x] = n;
}

__launch_bounds__(256)
__global__ void project_kernel(const void* __restrict__ li_feats, const void* __restrict__ ra_feats,
                               const void* __restrict__ li_nw, const void* __restrict__ li_nb,
                               const void* __restrict__ ra_nw, const void* __restrict__ ra_nb,
                               const int* __restrict__ flag, const float* __restrict__ wsW,
                               __hip_bfloat16* __restrict__ qOut, __hip_bfloat16* __restrict__ kOut,
                               __hip_bfloat16* __restrict__ vOut) {
    const int F = *flag;
    const int combo  = blockIdx.x / PBLK;     // 0..7 : tensor*4 + b
    const int blk    = blockIdx.x % PBLK;
    const int tensor = combo >> 2;            // 0 = li, 1 = ra
    const int b      = combo & 3;
    const int qd  = tensor;                   // li queries use dir0 weights, ra -> dir1
    const int kvd = 1 - tensor;               // li is kv for dir1, ra is kv for dir0

    __shared__ float wq[1024], wk[1024], wv[1024];
    __shared__ float bq[32], bk[32], bvv[32], nw[32], nb[32];
    const float* Wq  = wsW + qd  * WB_STRIDE;
    const float* Wkv = wsW + kvd * WB_STRIDE;
    for (int k = threadIdx.x; k < 1024; k += 256) {
        wq[k] = Wq[k];
        wk[k] = Wkv[1024 + k];
        wv[k] = Wkv[2048 + k];
    }
    if (threadIdx.x < 32) {
        bq[threadIdx.x]  = Wq[4096 + threadIdx.x];
        bk[threadIdx.x]  = Wkv[4128 + threadIdx.x];
        bvv[threadIdx.x] = Wkv[4160 + threadIdx.x];
        const void* w  = tensor ? ra_nw : li_nw;
        const void* bb = tensor ? ra_nb : li_nb;
        nw[threadIdx.x] = ldf(w, threadIdx.x, F);
        nb[threadIdx.x] = ldf(bb, threadIdx.x, F);
    }
    __syncthreads();

    const void* feats = tensor ? ra_feats : li_feats;
    const int lane = threadIdx.x & 31;
    const int sub  = threadIdx.x >> 5;   // 0..7

    for (int n0 = blk * 8; n0 < NN; n0 += PBLK * 8) {
        const int n = n0 + sub;
        if (n < NN) {
            const float x = ldf(feats, (b * NN + n) * CC + lane, F);
            float s = x;
            #pragma unroll
            for (int m = 1; m < 32; m <<= 1) s += __shfl_xor(s, m);
            const float mu = s * (1.f / 32.f);
            const float dx = x - mu;
            float s2 = dx * dx;
            #pragma unroll
            for (int m = 1; m < 32; m <<= 1) s2 += __shfl_xor(s2, m);
            const float var = s2 * (1.f / 32.f);
            const float xn = dx * rsqrtf(var + 1e-5f) * nw[lane] + nb[lane];

            float aq = bq[lane], ak = bk[lane], av = bvv[lane];
            #pragma unroll
            for (int t = 0; t < 32; ++t) {
                const float xb = __shfl(xn, t, 32);
                aq = fmaf(wq[t * 32 + lane], xb, aq);
                ak = fmaf(wk[t * 32 + lane], xb, ak);
                av = fmaf(wv[t * 32 + lane], xb, av);
            }
            const size_t off = ((size_t)(tensor * BB + b) * NN + n) * CC + lane;
            qOut[off] = __float2bfloat16(aq);
            kOut[off] = __float2bfloat16(ak);
            vOut[off] = __float2bfloat16(av);
        }
    }
}

__launch_bounds__(256)
__global__ void attn_kernel(const int* __restrict__ li_coors, const int* __restrict__ ra_coors,
                            const float* __restrict__ wsW, const int* __restrict__ lut,
                            const __hip_bfloat16* __restrict__ qArr, const __hip_bfloat16* __restrict__ kArr,
                            const __hip_bfloat16* __restrict__ vArr, __hip_bfloat16* __restrict__ resArr) {
    const int combo = blockIdx.x / ABLK;   // dir*4 + b
    const int blk   = blockIdx.x % ABLK;
    const int d = combo >> 2;
    const int b = combo & 3;
    const int qt = d;          // dir0: q = li(0); dir1: q = ra(1)
    const int kt = 1 - d;

    __shared__ float wo[1024], ob[32], bkr[32], bvr[32], pv[288];
    const float* Wd = wsW + d * WB_STRIDE;
    for (int k = threadIdx.x; k < 1024; k += 256) wo[k] = Wd[3072 + k];
    if (threadIdx.x < 32) {
        ob[threadIdx.x]  = Wd[4192 + threadIdx.x];
        bkr[threadIdx.x] = Wd[4224 + threadIdx.x];
        bvr[threadIdx.x] = Wd[4256 + threadIdx.x];
    }
    for (int k = threadIdx.x; k < 288; k += 256) pv[k] = Wd[4288 + k];
    __syncthreads();

    const int* qc = qt ? ra_coors : li_coors;
    const int* lutk = lut + (size_t)(kt * BB + b) * HWP;
    const __hip_bfloat16* kk = kArr + (size_t)(kt * BB + b) * NN * CC;
    const __hip_bfloat16* vv = vArr + (size_t)(kt * BB + b) * NN * CC;
    const __hip_bfloat16* qq = qArr + (size_t)(qt * BB + b) * NN * CC;
    __hip_bfloat16* res = resArr + (size_t)(d * BB + b) * NN * CC;

    const int lane = threadIdx.x & 31;
    const int sub  = threadIdx.x >> 5;

    for (int n0 = blk * 8; n0 < NN; n0 += ABLK * 8) {
        const int n = n0 + sub;
        if (n >= NN) continue;
        const float qv = bf(qq[(size_t)n * CC + lane]);   // read BEFORE res (aliased) write
        const int y = qc[(size_t)(b * NN + n) * 2 + 0];
        const int x = qc[(size_t)(b * NN + n) * 2 + 1];

        float sc[9], vr[9];
        #pragma unroll
        for (int s = 0; s < 9; ++s) {
            const int ny = y + c_SY[s], nx = x + c_SX[s];
            int idx = -1;
            if (ny >= 0 && ny < HH && nx >= 0 && nx < WW) idx = lutk[ny * WW + nx];
            float kc, vc;
            if (idx >= 0) {
                kc = bf(kk[(size_t)idx * CC + lane]);
                vc = bf(vv[(size_t)idx * CC + lane]) + pv[s * 32 + lane];
            } else {
                kc = bkr[lane];
                vc = bvr[lane];
            }
            vr[s] = vc;
            float p = qv * kc;
            p += __shfl_xor(p, 1);
            p += __shfl_xor(p, 2);
            p += __shfl_xor(p, 4);
            p += __shfl_xor(p, 8);   // sum over 16-lane head group
            sc[s] = p * 0.25f;       // 1/sqrt(16)
        }
        float m = sc[0];
        #pragma unroll
        for (int s = 1; s < 9; ++s) m = fmaxf(m, sc[s]);
        float den = 0.f, oc = 0.f;
        #pragma unroll
        for (int s = 0; s < 9; ++s) {
            const float e = __expf(sc[s] - m);
            den += e;
            oc = fmaf(e, vr[s], oc);
        }
        oc /= den;
        // out = o @ out_w.T + out_b
        float acc = ob[lane];
        #pragma unroll
        for (int j = 0; j < 32; ++j) {
            const float oj = __shfl(oc, j, 32);
            acc = fmaf(wo[j * 32 + lane], oj, acc);
        }
        res[(size_t)n * CC + lane] = __float2bfloat16(acc);
    }
}

// R4: LDS-staged transpose canvas. Gathers are b128 (4 lanes x 16 B per row =
// full 64-B lines used), stores are b128 (16 B/lane). LDS stride 33 floats:
// phase-2 writes and phase-3 reads are <=2-way bank aliased (free per m136).
__launch_bounds__(256)
__global__ void canvas_kernel(const int* __restrict__ lut, const __hip_bfloat16* __restrict__ resArr,
                              const int* __restrict__ flag, void* __restrict__ out) {
    const int F = *flag;
    const int tile = blockIdx.x % (HWP / 64);
    const int rem  = blockIdx.x / (HWP / 64);
    const int b = rem & 3;
    const int d = rem >> 2;
    const int* lutq = lut + (size_t)(d * BB + b) * HWP + (size_t)tile * 64;
    __shared__ int ls[64];
    __shared__ float st[64 * 33];
    const int t = threadIdx.x;
    if (t < 16) ((int4*)ls)[t] = ((const int4*)lutq)[t];
    __syncthreads();

    const __hip_bfloat16* res = resArr + (size_t)(d * BB + b) * NN * CC;
    {
        const int r = t >> 2, q = t & 3;   // row 0..63, 16-B chunk 0..3
        const int idx = ls[r];
        uint4 raw = make_uint4(0u, 0u, 0u, 0u);
        if (idx >= 0) raw = *(const uint4*)(res + (size_t)idx * CC + q * 8);
        float* dst = &st[r * 33 + q * 8];
        const unsigned int w0 = raw.x, w1 = raw.y, w2 = raw.z, w3 = raw.w;
        dst[0] = __uint_as_float((w0 & 0xFFFFu) << 16);
        dst[1] = __uint_as_float(w0 & 0xFFFF0000u);
        dst[2] = __uint_as_float((w1 & 0xFFFFu) << 16);
        dst[3] = __uint_as_float(w1 & 0xFFFF0000u);
        dst[4] = __uint_as_float((w2 & 0xFFFFu) << 16);
        dst[5] = __uint_as_float(w2 & 0xFFFF0000u);
        dst[6] = __uint_as_float((w3 & 0xFFFFu) << 16);
        dst[7] = __uint_as_float(w3 & 0xFFFF0000u);
    }
    __syncthreads();

    const int c = t >> 3, g = t & 7;   // channel 0..31, px-octet 0..7
    float v[8];
    #pragma unroll
    for (int j = 0; j < 8; ++j) v[j] = st[(8 * g + j) * 33 + c];
    const size_t obase = ((size_t)(d * BB + b) * CC + c) * HWP + (size_t)tile * 64 + 8 * g;
    if (F) {
        float* ob = (float*)out + obase;
        ((float4*)ob)[0] = make_float4(v[0], v[1], v[2], v[3]);
        ((float4*)ob)[1] = make_float4(v[4], v[5], v[6], v[7]);
    } else {
        __hip_bfloat16* ob = (__hip_bfloat16*)out + obase;
        __hip_bfloat16 h[8];
        #pragma unroll
        for (int j = 0; j < 8; ++j) h[j] = __float2bfloat16(v[j]);
        *(uint4*)ob = *(const uint4*)h;
    }
}

extern "C" void kernel_launch(void* const* d_in, const int* in_sizes, int n_in,
                              void* d_out, int out_size, void* d_ws, size_t ws_size,
                              hipStream_t stream) {
    (void)in_sizes; (void)n_in; (void)out_size; (void)ws_size;
    const void* li_feats = d_in[0];
    const void* ra_feats = d_in[1];
    const int* li_coors = (const int*)d_in[2];
    const int* ra_coors = (const int*)d_in[3];
    const void* li_nw = d_in[4];
    const void* li_nb = d_in[5];
    const void* ra_nw = d_in[6];
    const void* ra_nb = d_in[7];

    char* ws = (char*)d_ws;
    int*   flag = (int*)ws;                                   // 4 B
    float* wsW  = (float*)(ws + 512);                         // 36,864 B -> ends 37,376
    int*   lut  = (int*)(ws + 40960);                         // 6,422,528 B -> ends 6,463,488
    __hip_bfloat16* qArr = (__hip_bfloat16*)(ws + 6463488);   // 10,240,000 B each
    __hip_bfloat16* kArr = (__hip_bfloat16*)(ws + 16703488);
    __hip_bfloat16* vArr = (__hip_bfloat16*)(ws + 26943488);  // ends 37,183,488 (~35.5 MB)
    __hip_bfloat16* rArr = qArr;  // aliased: q[n] read only by the thread that writes res[n]

    prep_weights<<<2, 256, 0, stream>>>(d_in[8], d_in[9], d_in[10], d_in[11], d_in[12], d_in[13],
                                        d_in[14], d_in[15], d_in[16], d_in[17],
                                        d_in[18], d_in[19], d_in[20], d_in[21],
                                        li_feats, flag, wsW);
    hipMemsetAsync(lut, 0xFF, (size_t)2 * BB * HWP * sizeof(int), stream);
    build_lut<<<(2 * BB * NN + 255) / 256, 256, 0, stream>>>(li_coors, ra_coors, lut);
    project_kernel<<<8 * PBLK, 256, 0, stream>>>(li_feats, ra_feats, li_nw, li_nb, ra_nw, ra_nb,
                                                 flag, wsW, qArr, kArr, vArr);
    attn_kernel<<<8 * ABLK, 256, 0, stream>>>(li_coors, ra_coors, wsW, lut, qArr, kArr, vArr, rArr);
    canvas_kernel<<<2 * BB * (HWP / 64), 256, 0, stream>>>(lut, rArr, flag, d_out);
}

// Round 5
// 373.633 us; speedup vs baseline: 1.5876x; 1.1597x over previous
//
#include <hip/hip_runtime.h>
#include <hip/hip_bf16.h>

#define HH 448
#define WW 448
#define HWP (HH*WW)
#define CC 32
#define NN 20000
#define BB 4
#define PBLK 512
#define NPB 79   // ceil(20000/256) blocks per combo for attn

// SHIFTS = [[0,0],[-1,0],[1,0],[0,1],[-1,1],[1,1],[0,-1],[-1,-1],[1,-1]]
__constant__ int c_SY[9] = {0,-1,1,0,-1,1,0,-1,1};
__constant__ int c_SX[9] = {0,0,0,1,1,1,-1,-1,-1};

// Per-direction fused weight block layout (floats), stride 4608:
// [0:1024] WqT [1024:2048] WkT [2048:3072] WvT [3072:4096] WoT (wo[j*32+c])
// [4096] bq_f [4128] bk_f [4160] bv_f [4192] out_b
// [4224] bk_raw [4256] bv_raw [4288:4576] posv(9x32)
#define WB_STRIDE 4608

static __device__ __forceinline__ float bf(const __hip_bfloat16 v) {
    return __bfloat162float(v);
}
static __device__ __forceinline__ float ldf(const void* p, int i, int isf32) {
    if (isf32) return ((const float*)p)[i];
    return __bfloat162float(((const __hip_bfloat16*)p)[i]);
}
static __device__ __forceinline__ float blo(unsigned int u) { return __uint_as_float((u & 0xFFFFu) << 16); }
static __device__ __forceinline__ float bhi(unsigned int u) { return __uint_as_float(u & 0xFFFF0000u); }

static __device__ __forceinline__ void unpack8(uint4 r, float* f) {
    f[0]=blo(r.x); f[1]=bhi(r.x); f[2]=blo(r.y); f[3]=bhi(r.y);
    f[4]=blo(r.z); f[5]=bhi(r.z); f[6]=blo(r.w); f[7]=bhi(r.w);
}
static __device__ __forceinline__ float dot8(uint4 r, const float* q) {
    float a = 0.f;
    a = fmaf(blo(r.x), q[0], a); a = fmaf(bhi(r.x), q[1], a);
    a = fmaf(blo(r.y), q[2], a); a = fmaf(bhi(r.y), q[3], a);
    a = fmaf(blo(r.z), q[4], a); a = fmaf(bhi(r.z), q[5], a);
    a = fmaf(blo(r.w), q[6], a); a = fmaf(bhi(r.w), q[7], a);
    return a;
}
// o[0..7] += w * (unpack(r) + pv8), pv via two float4 broadcasts
static __device__ __forceinline__ void acc8(uint4 r, float w, float4 pA, float4 pB, float* o) {
    o[0]=fmaf(w, blo(r.x)+pA.x, o[0]); o[1]=fmaf(w, bhi(r.x)+pA.y, o[1]);
    o[2]=fmaf(w, blo(r.y)+pA.z, o[2]); o[3]=fmaf(w, bhi(r.y)+pA.w, o[3]);
    o[4]=fmaf(w, blo(r.z)+pB.x, o[4]); o[5]=fmaf(w, bhi(r.z)+pB.y, o[5]);
    o[6]=fmaf(w, blo(r.w)+pB.z, o[6]); o[7]=fmaf(w, bhi(r.w)+pB.w, o[7]);
}

// R5: prep (blocks 0,1) and build_lut (blocks 2..) fused into one dispatch.
__launch_bounds__(256)
__global__ void prep_build(const void* __restrict__ qkv1_w, const void* __restrict__ qkv1_b,
                           const void* __restrict__ qkv2_w, const void* __restrict__ qkv2_b,
                           const void* __restrict__ pos_w,  const void* __restrict__ pos_b,
                           const void* __restrict__ in1_w,  const void* __restrict__ in1_b,
                           const void* __restrict__ out1_w, const void* __restrict__ out1_b,
                           const void* __restrict__ in2_w,  const void* __restrict__ in2_b,
                           const void* __restrict__ out2_w, const void* __restrict__ out2_b,
                           const void* __restrict__ li_feats,
                           const int* __restrict__ li_coors, const int* __restrict__ ra_coors,
                           int* __restrict__ lut,
                           int* __restrict__ flag, float* __restrict__ wsW) {
    const int tid = threadIdx.x;
    if (blockIdx.x >= 2) {
        const int t = (blockIdx.x - 2) * 256 + tid;
        if (t >= 2 * BB * NN) return;
        const int tensor = t / (BB * NN);
        const int r = t % (BB * NN);
        const int b = r / NN, n = r % NN;
        const int* cc = tensor ? ra_coors : li_coors;
        const int y = cc[(size_t)(b * NN + n) * 2 + 0];
        const int x = cc[(size_t)(b * NN + n) * 2 + 1];
        lut[(size_t)(tensor * BB + b) * HWP + y * WW + x] = n;
        return;
    }
    __shared__ int cnt[256];
    {
        // dtype sniff: f32 data read as u16 pairs -> even words are mantissa
        // halves (~23% sane exponent); real bf16 N(0,1) -> ~100%.
        const unsigned short u = ((const unsigned short*)li_feats)[tid * 2];
        const int e = (u >> 7) & 0xFF;
        cnt[tid] = (u == 0 || (e >= 97 && e <= 157)) ? 1 : 0;
    }
    __syncthreads();
    for (int s = 128; s > 0; s >>= 1) {
        if (tid < s) cnt[tid] += cnt[tid + s];
        __syncthreads();
    }
    const int F = (cnt[0] >= 192) ? 0 : 1;   // 1 => f32
    if (blockIdx.x == 0 && tid == 0) *flag = F;

    const int d = blockIdx.x;
    const void* qw  = d ? qkv2_w : qkv1_w;
    const void* qb  = d ? qkv2_b : qkv1_b;
    const void* iw  = d ? in2_w  : in1_w;
    const void* ib  = d ? in2_b  : in1_b;
    const void* ow  = d ? out2_w : out1_w;
    const void* obp = d ? out2_b : out1_b;
    float* o = wsW + d * WB_STRIDE;

    __shared__ float s_qw[3072];
    __shared__ float s_iw[96 * 33];   // stride-33: lane-row access conflict-free
    __shared__ float s_ow[32 * 33];
    __shared__ float s_qb[96], s_ib[96], s_obp[32], s_pw[64], s_pb[32];

    if (F) {
        const float* fqw = (const float*)qw;  const float* fiw = (const float*)iw;
        const float* fow = (const float*)ow;  const float* fqb = (const float*)qb;
        const float* fib = (const float*)ib;  const float* fob = (const float*)obp;
        const float* fpw = (const float*)pos_w; const float* fpb = (const float*)pos_b;
        for (int i = tid; i < 3072; i += 256) s_qw[i] = fqw[i];
        for (int i = tid; i < 3072; i += 256) s_iw[(i >> 5) * 33 + (i & 31)] = fiw[i];
        for (int i = tid; i < 1024; i += 256) s_ow[(i >> 5) * 33 + (i & 31)] = fow[i];
        if (tid < 96) { s_qb[tid] = fqb[tid]; s_ib[tid] = fib[tid]; }
        if (tid < 64) s_pw[tid] = fpw[tid];
        if (tid < 32) { s_obp[tid] = fob[tid]; s_pb[tid] = fpb[tid]; }
    } else {
        const __hip_bfloat16* hqw = (const __hip_bfloat16*)qw;  const __hip_bfloat16* hiw = (const __hip_bfloat16*)iw;
        const __hip_bfloat16* how = (const __hip_bfloat16*)ow;  const __hip_bfloat16* hqb = (const __hip_bfloat16*)qb;
        const __hip_bfloat16* hib = (const __hip_bfloat16*)ib;  const __hip_bfloat16* hob = (const __hip_bfloat16*)obp;
        const __hip_bfloat16* hpw = (const __hip_bfloat16*)pos_w; const __hip_bfloat16* hpb = (const __hip_bfloat16*)pos_b;
        for (int i = tid; i < 3072; i += 256) s_qw[i] = bf(hqw[i]);
        for (int i = tid; i < 3072; i += 256) s_iw[(i >> 5) * 33 + (i & 31)] = bf(hiw[i]);
        for (int i = tid; i < 1024; i += 256) s_ow[(i >> 5) * 33 + (i & 31)] = bf(how[i]);
        if (tid < 96) { s_qb[tid] = bf(hqb[tid]); s_ib[tid] = bf(hib[tid]); }
        if (tid < 64) s_pw[tid] = bf(hpw[tid]);
        if (tid < 32) { s_obp[tid] = bf(hob[tid]); s_pb[tid] = bf(hpb[tid]); }
    }
    __syncthreads();

    for (int k = 0; k < 4; ++k) {
        const int idx = tid + k * 256;
        const int t = idx >> 5, i = idx & 31;
        float aq = 0.f, ak = 0.f, av = 0.f;
        #pragma unroll
        for (int u = 0; u < 32; ++u) {
            const float q0 = s_qw[u * 32 + t];
            const float q1 = s_qw[1024 + u * 32 + t];
            const float q2 = s_qw[2048 + u * 32 + t];
            aq = fmaf(s_iw[i * 33 + u],        q0, aq);
            ak = fmaf(s_iw[(32 + i) * 33 + u], q1, ak);
            av = fmaf(s_iw[(64 + i) * 33 + u], q2, av);
        }
        o[idx]        = aq;
        o[1024 + idx] = ak;
        o[2048 + idx] = av;
        o[3072 + idx] = s_ow[i * 33 + t];
    }
    if (tid < 32) {
        const int i = tid;
        float aq = 0.f, ak = 0.f, av = 0.f;
        #pragma unroll
        for (int u = 0; u < 32; ++u) {
            aq = fmaf(s_qb[u],      s_iw[i * 33 + u],        aq);
            ak = fmaf(s_qb[32 + u], s_iw[(32 + i) * 33 + u], ak);
            av = fmaf(s_qb[64 + u], s_iw[(64 + i) * 33 + u], av);
        }
        o[4096 + i] = aq + s_ib[i];
        o[4128 + i] = ak + s_ib[32 + i];
        o[4160 + i] = av + s_ib[64 + i];
        o[4192 + i] = s_obp[i];
        o[4224 + i] = s_ib[32 + i];
        o[4256 + i] = s_ib[64 + i];
    }
    for (int idx = tid; idx < 288; idx += 256) {
        const int s = idx >> 5, i = idx & 31;
        const float sy = (float)c_SY[s], sx = (float)c_SX[s];
        float acc = 0.f;
        #pragma unroll
        for (int j = 0; j < 32; ++j) {
            const float pj = sy * s_pw[j * 2 + 0] + sx * s_pw[j * 2 + 1] + s_pb[j];
            acc = fmaf(pj, s_iw[(64 + i) * 33 + j], acc);
        }
        o[4288 + idx] = acc;
    }
}

__launch_bounds__(256)
__global__ void project_kernel(const void* __restrict__ li_feats, const void* __restrict__ ra_feats,
                               const void* __restrict__ li_nw, const void* __restrict__ li_nb,
                               const void* __restrict__ ra_nw, const void* __restrict__ ra_nb,
                               const int* __restrict__ flag, const float* __restrict__ wsW,
                               __hip_bfloat16* __restrict__ qOut, __hip_bfloat16* __restrict__ kOut,
                               __hip_bfloat16* __restrict__ vOut) {
    const int F = *flag;
    const int combo  = blockIdx.x / PBLK;
    const int blk    = blockIdx.x % PBLK;
    const int tensor = combo >> 2;
    const int b      = combo & 3;
    const int qd  = tensor;
    const int kvd = 1 - tensor;

    __shared__ float wq[1024], wk[1024], wv[1024];
    __shared__ float bq[32], bk[32], bvv[32], nw[32], nb[32];
    const float* Wq  = wsW + qd  * WB_STRIDE;
    const float* Wkv = wsW + kvd * WB_STRIDE;
    for (int k = threadIdx.x; k < 1024; k += 256) {
        wq[k] = Wq[k];
        wk[k] = Wkv[1024 + k];
        wv[k] = Wkv[2048 + k];
    }
    if (threadIdx.x < 32) {
        bq[threadIdx.x]  = Wq[4096 + threadIdx.x];
        bk[threadIdx.x]  = Wkv[4128 + threadIdx.x];
        bvv[threadIdx.x] = Wkv[4160 + threadIdx.x];
        const void* w  = tensor ? ra_nw : li_nw;
        const void* bb = tensor ? ra_nb : li_nb;
        nw[threadIdx.x] = ldf(w, threadIdx.x, F);
        nb[threadIdx.x] = ldf(bb, threadIdx.x, F);
    }
    __syncthreads();

    const void* feats = tensor ? ra_feats : li_feats;
    const int lane = threadIdx.x & 31;
    const int sub  = threadIdx.x >> 5;

    for (int n0 = blk * 8; n0 < NN; n0 += PBLK * 8) {
        const int n = n0 + sub;
        if (n < NN) {
            const float x = ldf(feats, (b * NN + n) * CC + lane, F);
            float s = x;
            #pragma unroll
            for (int m = 1; m < 32; m <<= 1) s += __shfl_xor(s, m);
            const float mu = s * (1.f / 32.f);
            const float dx = x - mu;
            float s2 = dx * dx;
            #pragma unroll
            for (int m = 1; m < 32; m <<= 1) s2 += __shfl_xor(s2, m);
            const float var = s2 * (1.f / 32.f);
            const float xn = dx * rsqrtf(var + 1e-5f) * nw[lane] + nb[lane];

            float aq = bq[lane], ak = bk[lane], av = bvv[lane];
            #pragma unroll
            for (int t = 0; t < 32; ++t) {
                const float xb = __shfl(xn, t, 32);
                aq = fmaf(wq[t * 32 + lane], xb, aq);
                ak = fmaf(wk[t * 32 + lane], xb, ak);
                av = fmaf(wv[t * 32 + lane], xb, av);
            }
            const size_t off = ((size_t)(tensor * BB + b) * NN + n) * CC + lane;
            qOut[off] = __float2bfloat16(aq);
            kOut[off] = __float2bfloat16(ak);
            vOut[off] = __float2bfloat16(av);
        }
    }
}

// R5: one point per LANE. All softmax/score/V math is per-lane VALU (zero
// ds_bpermute); k/v rows gathered as 4x uint4 (full 64-B rows); out-proj via
// lane-uniform float4 LDS broadcasts (256 per wave serving 64 points).
__launch_bounds__(256)
__global__ void attn_kernel(const int* __restrict__ li_coors, const int* __restrict__ ra_coors,
                            const float* __restrict__ wsW, const int* __restrict__ lut,
                            const __hip_bfloat16* __restrict__ qArr, const __hip_bfloat16* __restrict__ kArr,
                            const __hip_bfloat16* __restrict__ vArr, __hip_bfloat16* __restrict__ resArr) {
    const int combo = blockIdx.x / NPB;   // dir*4 + b
    const int n     = (blockIdx.x % NPB) * 256 + threadIdx.x;
    const int d = combo >> 2;
    const int b = combo & 3;
    const int qt = d, kt = 1 - d;

    __shared__ __align__(16) float wo[1024];
    __shared__ __align__(16) float pv[288];
    __shared__ __align__(16) float ob[32], bkr[32], bvr[32];
    const float* Wd = wsW + d * WB_STRIDE;
    for (int k = threadIdx.x; k < 1024; k += 256) wo[k] = Wd[3072 + k];
    if (threadIdx.x < 32) {
        ob[threadIdx.x]  = Wd[4192 + threadIdx.x];
        bkr[threadIdx.x] = Wd[4224 + threadIdx.x];
        bvr[threadIdx.x] = Wd[4256 + threadIdx.x];
    }
    for (int k = threadIdx.x; k < 288; k += 256) pv[k] = Wd[4288 + k];
    __syncthreads();
    if (n >= NN) return;

    const int* qc = qt ? ra_coors : li_coors;
    const int* lutk = lut + (size_t)(kt * BB + b) * HWP;
    const __hip_bfloat16* kk = kArr + (size_t)(kt * BB + b) * NN * CC;
    const __hip_bfloat16* vv = vArr + (size_t)(kt * BB + b) * NN * CC;
    const __hip_bfloat16* qq = qArr + (size_t)(qt * BB + b) * NN * CC;
    __hip_bfloat16* res = resArr + (size_t)(d * BB + b) * NN * CC;

    float q[32];
    {
        const uint4* qr = (const uint4*)(qq + (size_t)n * CC);
        unpack8(qr[0], q); unpack8(qr[1], q + 8);
        unpack8(qr[2], q + 16); unpack8(qr[3], q + 24);
    }
    const int y = qc[(size_t)(b * NN + n) * 2 + 0];
    const int x = qc[(size_t)(b * NN + n) * 2 + 1];
    int idx[9];
    #pragma unroll
    for (int s = 0; s < 9; ++s) {
        const int ny = y + c_SY[s], nx = x + c_SX[s];
        idx[s] = (ny >= 0 && ny < HH && nx >= 0 && nx < WW) ? lutk[ny * WW + nx] : -1;
    }
    // invalid-neighbor k is the constant bk_raw vector: dot once per head
    float di0 = 0.f, di1 = 0.f;
    #pragma unroll
    for (int c = 0; c < 16; ++c) di0 = fmaf(q[c], bkr[c], di0);
    #pragma unroll
    for (int c = 16; c < 32; ++c) di1 = fmaf(q[c], bkr[c], di1);

    float s0[9], s1[9];
    #pragma unroll
    for (int s = 0; s < 9; ++s) {
        float d0, d1;
        if (idx[s] >= 0) {
            const uint4* kr = (const uint4*)(kk + (size_t)idx[s] * CC);
            const uint4 r0 = kr[0], r1 = kr[1], r2 = kr[2], r3 = kr[3];
            d0 = dot8(r0, q) + dot8(r1, q + 8);
            d1 = dot8(r2, q + 16) + dot8(r3, q + 24);
        } else { d0 = di0; d1 = di1; }
        s0[s] = d0 * 0.25f;   // 1/sqrt(16)
        s1[s] = d1 * 0.25f;
    }
    float m0 = s0[0], m1 = s1[0];
    #pragma unroll
    for (int s = 1; s < 9; ++s) { m0 = fmaxf(m0, s0[s]); m1 = fmaxf(m1, s1[s]); }
    float e0[9], e1[9], den0 = 0.f, den1 = 0.f;
    #pragma unroll
    for (int s = 0; s < 9; ++s) {
        e0[s] = __expf(s0[s] - m0); den0 += e0[s];
        e1[s] = __expf(s1[s] - m1); den1 += e1[s];
    }
    const float i0 = 1.f / den0, i1 = 1.f / den1;

    float o[32];
    #pragma unroll
    for (int c = 0; c < 32; ++c) o[c] = 0.f;
    float wi0 = 0.f, wi1 = 0.f;
    const float4* pv4 = (const float4*)pv;
    #pragma unroll
    for (int s = 0; s < 9; ++s) {
        const float w0 = e0[s] * i0, w1 = e1[s] * i1;
        if (idx[s] >= 0) {
            const uint4* vr = (const uint4*)(vv + (size_t)idx[s] * CC);
            const uint4 r0 = vr[0], r1 = vr[1], r2 = vr[2], r3 = vr[3];
            acc8(r0, w0, pv4[s * 8 + 0], pv4[s * 8 + 1], o);
            acc8(r1, w0, pv4[s * 8 + 2], pv4[s * 8 + 3], o + 8);
            acc8(r2, w1, pv4[s * 8 + 4], pv4[s * 8 + 5], o + 16);
            acc8(r3, w1, pv4[s * 8 + 6], pv4[s * 8 + 7], o + 24);
        } else { wi0 += w0; wi1 += w1; }
    }
    #pragma unroll
    for (int c = 0; c < 16; ++c) o[c] = fmaf(wi0, bvr[c], o[c]);
    #pragma unroll
    for (int c = 16; c < 32; ++c) o[c] = fmaf(wi1, bvr[c], o[c]);

    // out = o @ out_w.T + out_b, weights via float4 LDS broadcasts
    float out[32];
    const float4* ob4 = (const float4*)ob;
    #pragma unroll
    for (int i4 = 0; i4 < 8; ++i4) {
        const float4 t = ob4[i4];
        out[i4 * 4 + 0] = t.x; out[i4 * 4 + 1] = t.y;
        out[i4 * 4 + 2] = t.z; out[i4 * 4 + 3] = t.w;
    }
    #pragma unroll
    for (int j = 0; j < 32; ++j) {
        const float oj = o[j];
        const float4* wr = (const float4*)&wo[j * 32];
        #pragma unroll
        for (int i4 = 0; i4 < 8; ++i4) {
            const float4 w = wr[i4];
            out[i4 * 4 + 0] = fmaf(oj, w.x, out[i4 * 4 + 0]);
            out[i4 * 4 + 1] = fmaf(oj, w.y, out[i4 * 4 + 1]);
            out[i4 * 4 + 2] = fmaf(oj, w.z, out[i4 * 4 + 2]);
            out[i4 * 4 + 3] = fmaf(oj, w.w, out[i4 * 4 + 3]);
        }
    }
    __hip_bfloat16 hb[32];
    #pragma unroll
    for (int c = 0; c < 32; ++c) hb[c] = __float2bfloat16(out[c]);
    uint4* rp = (uint4*)(res + (size_t)n * CC);
    const uint4* hp = (const uint4*)hb;
    rp[0] = hp[0]; rp[1] = hp[1]; rp[2] = hp[2]; rp[3] = hp[3];
}

__launch_bounds__(256)
__global__ void canvas_kernel(const int* __restrict__ lut, const __hip_bfloat16* __restrict__ resArr,
                              const int* __restrict__ flag, void* __restrict__ out) {
    const int F = *flag;
    const int tile = blockIdx.x % (HWP / 64);
    const int rem  = blockIdx.x / (HWP / 64);
    const int b = rem & 3;
    const int d = rem >> 2;
    const int* lutq = lut + (size_t)(d * BB + b) * HWP + (size_t)tile * 64;
    __shared__ int ls[64];
    __shared__ float st[64 * 33];
    const int t = threadIdx.x;
    if (t < 16) ((int4*)ls)[t] = ((const int4*)lutq)[t];
    __syncthreads();

    const __hip_bfloat16* res = resArr + (size_t)(d * BB + b) * NN * CC;
    {
        const int r = t >> 2, q = t & 3;
        const int idx = ls[r];
        uint4 raw = make_uint4(0u, 0u, 0u, 0u);
        if (idx >= 0) raw = *(const uint4*)(res + (size_t)idx * CC + q * 8);
        float* dst = &st[r * 33 + q * 8];
        dst[0] = blo(raw.x); dst[1] = bhi(raw.x);
        dst[2] = blo(raw.y); dst[3] = bhi(raw.y);
        dst[4] = blo(raw.z); dst[5] = bhi(raw.z);
        dst[6] = blo(raw.w); dst[7] = bhi(raw.w);
    }
    __syncthreads();

    const int c = t >> 3, g = t & 7;
    float v[8];
    #pragma unroll
    for (int j = 0; j < 8; ++j) v[j] = st[(8 * g + j) * 33 + c];
    const size_t obase = ((size_t)(d * BB + b) * CC + c) * HWP + (size_t)tile * 64 + 8 * g;
    if (F) {
        float* ob = (float*)out + obase;
        ((float4*)ob)[0] = make_float4(v[0], v[1], v[2], v[3]);
        ((float4*)ob)[1] = make_float4(v[4], v[5], v[6], v[7]);
    } else {
        __hip_bfloat16* ob = (__hip_bfloat16*)out + obase;
        __hip_bfloat16 h[8];
        #pragma unroll
        for (int j = 0; j < 8; ++j) h[j] = __float2bfloat16(v[j]);
        *(uint4*)ob = *(const uint4*)h;
    }
}

extern "C" void kernel_launch(void* const* d_in, const int* in_sizes, int n_in,
                              void* d_out, int out_size, void* d_ws, size_t ws_size,
                              hipStream_t stream) {
    (void)in_sizes; (void)n_in; (void)out_size; (void)ws_size;
    const void* li_feats = d_in[0];
    const void* ra_feats = d_in[1];
    const int* li_coors = (const int*)d_in[2];
    const int* ra_coors = (const int*)d_in[3];
    const void* li_nw = d_in[4];
    const void* li_nb = d_in[5];
    const void* ra_nw = d_in[6];
    const void* ra_nb = d_in[7];

    char* ws = (char*)d_ws;
    int*   flag = (int*)ws;
    float* wsW  = (float*)(ws + 512);
    int*   lut  = (int*)(ws + 40960);
    __hip_bfloat16* qArr = (__hip_bfloat16*)(ws + 6463488);
    __hip_bfloat16* kArr = (__hip_bfloat16*)(ws + 16703488);
    __hip_bfloat16* vArr = (__hip_bfloat16*)(ws + 26943488);
    __hip_bfloat16* rArr = qArr;  // aliased: q[n] read only by the lane that writes res[n]

    hipMemsetAsync(lut, 0xFF, (size_t)2 * BB * HWP * sizeof(int), stream);
    const int buildBlocks = (2 * BB * NN + 255) / 256;
    prep_build<<<2 + buildBlocks, 256, 0, stream>>>(d_in[8], d_in[9], d_in[10], d_in[11], d_in[12], d_in[13],
                                                    d_in[14], d_in[15], d_in[16], d_in[17],
                                                    d_in[18], d_in[19], d_in[20], d_in[21],
                                                    li_feats, li_coors, ra_coors, lut, flag, wsW);
    project_kernel<<<8 * PBLK, 256, 0, stream>>>(li_feats, ra_feats, li_nw, li_nb, ra_nw, ra_nb,
                                                 flag, wsW, qArr, kArr, vArr);
    attn_kernel<<<8 * NPB, 256, 0, stream>>>(li_coors, ra_coors, wsW, lut, qArr, kArr, vArr, rArr);
    canvas_kernel<<<2 * BB * (HWP / 64), 256, 0, stream>>>(lut, rArr, flag, d_out);
}

// Round 6
// 332.256 us; speedup vs baseline: 1.7853x; 1.1245x over previous
//
#include <hip/hip_runtime.h>
#include <hip/hip_bf16.h>

#define HH 448
#define WW 448
#define HWP (HH*WW)
#define CC 32
#define NN 20000
#define BB 4
#define NPB 79   // ceil(20000/256) blocks per combo

// SHIFTS = [[0,0],[-1,0],[1,0],[0,1],[-1,1],[1,1],[0,-1],[-1,-1],[1,-1]]
__constant__ int c_SY[9] = {0,-1,1,0,-1,1,0,-1,1};
__constant__ int c_SX[9] = {0,0,0,1,1,1,-1,-1,-1};

// Per-direction fused weight block layout (floats), stride 4608:
// [0:1024] WqT [1024:2048] WkT [2048:3072] WvT [3072:4096] WoT (wo[j*32+c])
// [4096] bq_f [4128] bk_f [4160] bv_f [4192] out_b
// [4224] bk_raw [4256] bv_raw [4288:4576] posv(9x32)
#define WB_STRIDE 4608

static __device__ __forceinline__ float bf(const __hip_bfloat16 v) {
    return __bfloat162float(v);
}
static __device__ __forceinline__ float ldf(const void* p, int i, int isf32) {
    if (isf32) return ((const float*)p)[i];
    return __bfloat162float(((const __hip_bfloat16*)p)[i]);
}
static __device__ __forceinline__ float blo(unsigned int u) { return __uint_as_float((u & 0xFFFFu) << 16); }
static __device__ __forceinline__ float bhi(unsigned int u) { return __uint_as_float(u & 0xFFFF0000u); }

static __device__ __forceinline__ void unpack8(uint4 r, float* f) {
    f[0]=blo(r.x); f[1]=bhi(r.x); f[2]=blo(r.y); f[3]=bhi(r.y);
    f[4]=blo(r.z); f[5]=bhi(r.z); f[6]=blo(r.w); f[7]=bhi(r.w);
}
static __device__ __forceinline__ float dot8(uint4 r, const float* q) {
    float a = 0.f;
    a = fmaf(blo(r.x), q[0], a); a = fmaf(bhi(r.x), q[1], a);
    a = fmaf(blo(r.y), q[2], a); a = fmaf(bhi(r.y), q[3], a);
    a = fmaf(blo(r.z), q[4], a); a = fmaf(bhi(r.z), q[5], a);
    a = fmaf(blo(r.w), q[6], a); a = fmaf(bhi(r.w), q[7], a);
    return a;
}
// o[0..7] += w * (unpack(r) + pv8)
static __device__ __forceinline__ void acc8(uint4 r, float w, float4 pA, float4 pB, float* o) {
    o[0]=fmaf(w, blo(r.x)+pA.x, o[0]); o[1]=fmaf(w, bhi(r.x)+pA.y, o[1]);
    o[2]=fmaf(w, blo(r.y)+pA.z, o[2]); o[3]=fmaf(w, bhi(r.y)+pA.w, o[3]);
    o[4]=fmaf(w, blo(r.z)+pB.x, o[4]); o[5]=fmaf(w, bhi(r.z)+pB.y, o[5]);
    o[6]=fmaf(w, blo(r.w)+pB.z, o[6]); o[7]=fmaf(w, bhi(r.w)+pB.w, o[7]);
}
static __device__ __forceinline__ void store32bf(__hip_bfloat16* p, const float* a) {
    __hip_bfloat16 h[32];
    #pragma unroll
    for (int c = 0; c < 32; ++c) h[c] = __float2bfloat16(a[c]);
    uint4* rp = (uint4*)p; const uint4* hp = (const uint4*)h;
    rp[0] = hp[0]; rp[1] = hp[1]; rp[2] = hp[2]; rp[3] = hp[3];
}

// prep (blocks 0,1) and build_lut (blocks 2..) fused into one dispatch.
__launch_bounds__(256)
__global__ void prep_build(const void* __restrict__ qkv1_w, const void* __restrict__ qkv1_b,
                           const void* __restrict__ qkv2_w, const void* __restrict__ qkv2_b,
                           const void* __restrict__ pos_w,  const void* __restrict__ pos_b,
                           const void* __restrict__ in1_w,  const void* __restrict__ in1_b,
                           const void* __restrict__ out1_w, const void* __restrict__ out1_b,
                           const void* __restrict__ in2_w,  const void* __restrict__ in2_b,
                           const void* __restrict__ out2_w, const void* __restrict__ out2_b,
                           const void* __restrict__ li_feats,
                           const int* __restrict__ li_coors, const int* __restrict__ ra_coors,
                           int* __restrict__ lut,
                           int* __restrict__ flag, float* __restrict__ wsW) {
    const int tid = threadIdx.x;
    if (blockIdx.x >= 2) {
        const int t = (blockIdx.x - 2) * 256 + tid;
        if (t >= 2 * BB * NN) return;
        const int tensor = t / (BB * NN);
        const int r = t % (BB * NN);
        const int b = r / NN, n = r % NN;
        const int* cc = tensor ? ra_coors : li_coors;
        const int y = cc[(size_t)(b * NN + n) * 2 + 0];
        const int x = cc[(size_t)(b * NN + n) * 2 + 1];
        lut[(size_t)(tensor * BB + b) * HWP + y * WW + x] = n;
        return;
    }
    __shared__ int cnt[256];
    {
        // dtype sniff: f32 data read as u16 pairs -> even words are mantissa
        // halves (~23% sane exponent); real bf16 N(0,1) -> ~100%.
        const unsigned short u = ((const unsigned short*)li_feats)[tid * 2];
        const int e = (u >> 7) & 0xFF;
        cnt[tid] = (u == 0 || (e >= 97 && e <= 157)) ? 1 : 0;
    }
    __syncthreads();
    for (int s = 128; s > 0; s >>= 1) {
        if (tid < s) cnt[tid] += cnt[tid + s];
        __syncthreads();
    }
    const int F = (cnt[0] >= 192) ? 0 : 1;   // 1 => f32
    if (blockIdx.x == 0 && tid == 0) *flag = F;

    const int d = blockIdx.x;
    const void* qw  = d ? qkv2_w : qkv1_w;
    const void* qb  = d ? qkv2_b : qkv1_b;
    const void* iw  = d ? in2_w  : in1_w;
    const void* ib  = d ? in2_b  : in1_b;
    const void* ow  = d ? out2_w : out1_w;
    const void* obp = d ? out2_b : out1_b;
    float* o = wsW + d * WB_STRIDE;

    __shared__ float s_qw[3072];
    __shared__ float s_iw[96 * 33];   // stride-33: lane-row access conflict-free
    __shared__ float s_ow[32 * 33];
    __shared__ float s_qb[96], s_ib[96], s_obp[32], s_pw[64], s_pb[32];

    if (F) {
        const float* fqw = (const float*)qw;  const float* fiw = (const float*)iw;
        const float* fow = (const float*)ow;  const float* fqb = (const float*)qb;
        const float* fib = (const float*)ib;  const float* fob = (const float*)obp;
        const float* fpw = (const float*)pos_w; const float* fpb = (const float*)pos_b;
        for (int i = tid; i < 3072; i += 256) s_qw[i] = fqw[i];
        for (int i = tid; i < 3072; i += 256) s_iw[(i >> 5) * 33 + (i & 31)] = fiw[i];
        for (int i = tid; i < 1024; i += 256) s_ow[(i >> 5) * 33 + (i & 31)] = fow[i];
        if (tid < 96) { s_qb[tid] = fqb[tid]; s_ib[tid] = fib[tid]; }
        if (tid < 64) s_pw[tid] = fpw[tid];
        if (tid < 32) { s_obp[tid] = fob[tid]; s_pb[tid] = fpb[tid]; }
    } else {
        const __hip_bfloat16* hqw = (const __hip_bfloat16*)qw;  const __hip_bfloat16* hiw = (const __hip_bfloat16*)iw;
        const __hip_bfloat16* how = (const __hip_bfloat16*)ow;  const __hip_bfloat16* hqb = (const __hip_bfloat16*)qb;
        const __hip_bfloat16* hib = (const __hip_bfloat16*)ib;  const __hip_bfloat16* hob = (const __hip_bfloat16*)obp;
        const __hip_bfloat16* hpw = (const __hip_bfloat16*)pos_w; const __hip_bfloat16* hpb = (const __hip_bfloat16*)pos_b;
        for (int i = tid; i < 3072; i += 256) s_qw[i] = bf(hqw[i]);
        for (int i = tid; i < 3072; i += 256) s_iw[(i >> 5) * 33 + (i & 31)] = bf(hiw[i]);
        for (int i = tid; i < 1024; i += 256) s_ow[(i >> 5) * 33 + (i & 31)] = bf(how[i]);
        if (tid < 96) { s_qb[tid] = bf(hqb[tid]); s_ib[tid] = bf(hib[tid]); }
        if (tid < 64) s_pw[tid] = bf(hpw[tid]);
        if (tid < 32) { s_obp[tid] = bf(hob[tid]); s_pb[tid] = bf(hpb[tid]); }
    }
    __syncthreads();

    for (int k = 0; k < 4; ++k) {
        const int idx = tid + k * 256;
        const int t = idx >> 5, i = idx & 31;
        float aq = 0.f, ak = 0.f, av = 0.f;
        #pragma unroll
        for (int u = 0; u < 32; ++u) {
            const float q0 = s_qw[u * 32 + t];
            const float q1 = s_qw[1024 + u * 32 + t];
            const float q2 = s_qw[2048 + u * 32 + t];
            aq = fmaf(s_iw[i * 33 + u],        q0, aq);
            ak = fmaf(s_iw[(32 + i) * 33 + u], q1, ak);
            av = fmaf(s_iw[(64 + i) * 33 + u], q2, av);
        }
        o[idx]        = aq;
        o[1024 + idx] = ak;
        o[2048 + idx] = av;
        o[3072 + idx] = s_ow[i * 33 + t];
    }
    if (tid < 32) {
        const int i = tid;
        float aq = 0.f, ak = 0.f, av = 0.f;
        #pragma unroll
        for (int u = 0; u < 32; ++u) {
            aq = fmaf(s_qb[u],      s_iw[i * 33 + u],        aq);
            ak = fmaf(s_qb[32 + u], s_iw[(32 + i) * 33 + u], ak);
            av = fmaf(s_qb[64 + u], s_iw[(64 + i) * 33 + u], av);
        }
        o[4096 + i] = aq + s_ib[i];
        o[4128 + i] = ak + s_ib[32 + i];
        o[4160 + i] = av + s_ib[64 + i];
        o[4192 + i] = s_obp[i];
        o[4224 + i] = s_ib[32 + i];
        o[4256 + i] = s_ib[64 + i];
    }
    for (int idx = tid; idx < 288; idx += 256) {
        const int s = idx >> 5, i = idx & 31;
        const float sy = (float)c_SY[s], sx = (float)c_SX[s];
        float acc = 0.f;
        #pragma unroll
        for (int j = 0; j < 32; ++j) {
            const float pj = sy * s_pw[j * 2 + 0] + sx * s_pw[j * 2 + 1] + s_pb[j];
            acc = fmaf(pj, s_iw[(64 + i) * 33 + j], acc);
        }
        o[4288 + idx] = acc;
    }
}

// R6: one point per LANE; LN in registers; weight matmuls stream wave-uniform
// float4 reads straight from wsW (scalarizable to s_load on the scalar pipe —
// zero DS, zero shuffles). Old shuffle version cost ~126 DS-cy/pt.
__launch_bounds__(256)
__global__ void project_kernel(const void* __restrict__ li_feats, const void* __restrict__ ra_feats,
                               const void* __restrict__ li_nw, const void* __restrict__ li_nb,
                               const void* __restrict__ ra_nw, const void* __restrict__ ra_nb,
                               const int* __restrict__ flag, const float* __restrict__ wsW,
                               __hip_bfloat16* __restrict__ qOut, __hip_bfloat16* __restrict__ kOut,
                               __hip_bfloat16* __restrict__ vOut) {
    const int F = *flag;
    const int combo  = blockIdx.x / NPB;      // tensor*4 + b
    const int n      = (blockIdx.x % NPB) * 256 + threadIdx.x;
    if (n >= NN) return;
    const int tensor = combo >> 2;
    const int b      = combo & 3;
    const float* Wq  = wsW + tensor * WB_STRIDE;       // q uses own-direction weights
    const float* Wkv = wsW + (1 - tensor) * WB_STRIDE; // k/v serve the other direction

    const void* feats = tensor ? ra_feats : li_feats;
    const void* nwp   = tensor ? ra_nw : li_nw;
    const void* nbp   = tensor ? ra_nb : li_nb;

    float x[32];
    if (F) {
        const float4* fr = (const float4*)((const float*)feats + (size_t)(b * NN + n) * CC);
        #pragma unroll
        for (int i = 0; i < 8; ++i) {
            const float4 t = fr[i];
            x[4*i] = t.x; x[4*i+1] = t.y; x[4*i+2] = t.z; x[4*i+3] = t.w;
        }
    } else {
        const uint4* hr = (const uint4*)((const __hip_bfloat16*)feats + (size_t)(b * NN + n) * CC);
        unpack8(hr[0], x); unpack8(hr[1], x + 8);
        unpack8(hr[2], x + 16); unpack8(hr[3], x + 24);
    }
    float s = 0.f;
    #pragma unroll
    for (int c = 0; c < 32; ++c) s += x[c];
    const float mu = s * (1.f / 32.f);
    float s2 = 0.f;
    #pragma unroll
    for (int c = 0; c < 32; ++c) { const float dx = x[c] - mu; s2 += dx * dx; }
    const float rs = rsqrtf(s2 * (1.f / 32.f) + 1e-5f);
    #pragma unroll
    for (int c = 0; c < 32; ++c)
        x[c] = (x[c] - mu) * rs * ldf(nwp, c, F) + ldf(nbp, c, F);   // uniform nw/nb reads

    const size_t off = ((size_t)(tensor * BB + b) * NN + n) * CC;
    // three sequential 32x32 matmul passes; weights via uniform float4 reads
    #pragma unroll
    for (int pass = 0; pass < 3; ++pass) {
        const float* W = (pass == 0) ? Wq : Wkv + pass * 1024;
        const float* Bv = (pass == 0) ? (Wq + 4096) : (Wkv + 4096 + pass * 32);
        float a[32];
        const float4* b4 = (const float4*)Bv;
        #pragma unroll
        for (int i4 = 0; i4 < 8; ++i4) {
            const float4 t = b4[i4];
            a[4*i4] = t.x; a[4*i4+1] = t.y; a[4*i4+2] = t.z; a[4*i4+3] = t.w;
        }
        #pragma unroll
        for (int j = 0; j < 32; ++j) {
            const float xj = x[j];
            const float4* wr = (const float4*)&W[j * 32];
            #pragma unroll
            for (int i4 = 0; i4 < 8; ++i4) {
                const float4 w = wr[i4];
                a[4*i4+0] = fmaf(xj, w.x, a[4*i4+0]);
                a[4*i4+1] = fmaf(xj, w.y, a[4*i4+1]);
                a[4*i4+2] = fmaf(xj, w.z, a[4*i4+2]);
                a[4*i4+3] = fmaf(xj, w.w, a[4*i4+3]);
            }
        }
        store32bf((pass == 0 ? qOut : pass == 1 ? kOut : vOut) + off, a);
    }
}

// One point per lane; weights/bias/posv all wave-uniform reads from wsW
// (no LDS, no barriers). k/v rows gathered as 4x uint4 (full 64-B rows).
__launch_bounds__(256)
__global__ void attn_kernel(const int* __restrict__ li_coors, const int* __restrict__ ra_coors,
                            const float* __restrict__ wsW, const int* __restrict__ lut,
                            const __hip_bfloat16* __restrict__ qArr, const __hip_bfloat16* __restrict__ kArr,
                            const __hip_bfloat16* __restrict__ vArr, __hip_bfloat16* __restrict__ resArr) {
    const int combo = blockIdx.x / NPB;   // dir*4 + b
    const int n     = (blockIdx.x % NPB) * 256 + threadIdx.x;
    if (n >= NN) return;
    const int d = combo >> 2;
    const int b = combo & 3;
    const int qt = d, kt = 1 - d;
    const float* Wd = wsW + d * WB_STRIDE;

    const int* qc = qt ? ra_coors : li_coors;
    const int* lutk = lut + (size_t)(kt * BB + b) * HWP;
    const __hip_bfloat16* kk = kArr + (size_t)(kt * BB + b) * NN * CC;
    const __hip_bfloat16* vv = vArr + (size_t)(kt * BB + b) * NN * CC;
    const __hip_bfloat16* qq = qArr + (size_t)(qt * BB + b) * NN * CC;
    __hip_bfloat16* res = resArr + (size_t)(d * BB + b) * NN * CC;

    float q[32];
    {
        const uint4* qr = (const uint4*)(qq + (size_t)n * CC);
        unpack8(qr[0], q); unpack8(qr[1], q + 8);
        unpack8(qr[2], q + 16); unpack8(qr[3], q + 24);
    }
    const int y = qc[(size_t)(b * NN + n) * 2 + 0];
    const int x = qc[(size_t)(b * NN + n) * 2 + 1];
    int idx[9];
    #pragma unroll
    for (int s = 0; s < 9; ++s) {
        const int ny = y + c_SY[s], nx = x + c_SX[s];
        idx[s] = (ny >= 0 && ny < HH && nx >= 0 && nx < WW) ? lutk[ny * WW + nx] : -1;
    }
    // invalid-neighbor k is the constant bk_raw vector: dot once per head
    float di0 = 0.f, di1 = 0.f;
    #pragma unroll
    for (int c = 0; c < 16; ++c) di0 = fmaf(q[c], Wd[4224 + c], di0);
    #pragma unroll
    for (int c = 16; c < 32; ++c) di1 = fmaf(q[c], Wd[4224 + c], di1);

    float s0[9], s1[9];
    #pragma unroll
    for (int s = 0; s < 9; ++s) {
        float d0, d1;
        if (idx[s] >= 0) {
            const uint4* kr = (const uint4*)(kk + (size_t)idx[s] * CC);
            const uint4 r0 = kr[0], r1 = kr[1], r2 = kr[2], r3 = kr[3];
            d0 = dot8(r0, q) + dot8(r1, q + 8);
            d1 = dot8(r2, q + 16) + dot8(r3, q + 24);
        } else { d0 = di0; d1 = di1; }
        s0[s] = d0 * 0.25f;   // 1/sqrt(16)
        s1[s] = d1 * 0.25f;
    }
    float m0 = s0[0], m1 = s1[0];
    #pragma unroll
    for (int s = 1; s < 9; ++s) { m0 = fmaxf(m0, s0[s]); m1 = fmaxf(m1, s1[s]); }
    float e0[9], e1[9], den0 = 0.f, den1 = 0.f;
    #pragma unroll
    for (int s = 0; s < 9; ++s) {
        e0[s] = __expf(s0[s] - m0); den0 += e0[s];
        e1[s] = __expf(s1[s] - m1); den1 += e1[s];
    }
    const float i0 = 1.f / den0, i1 = 1.f / den1;

    float o[32];
    #pragma unroll
    for (int c = 0; c < 32; ++c) o[c] = 0.f;
    float wi0 = 0.f, wi1 = 0.f;
    const float4* pv4 = (const float4*)&Wd[4288];
    #pragma unroll
    for (int s = 0; s < 9; ++s) {
        const float w0 = e0[s] * i0, w1 = e1[s] * i1;
        if (idx[s] >= 0) {
            const uint4* vr = (const uint4*)(vv + (size_t)idx[s] * CC);
            const uint4 r0 = vr[0], r1 = vr[1], r2 = vr[2], r3 = vr[3];
            acc8(r0, w0, pv4[s * 8 + 0], pv4[s * 8 + 1], o);
            acc8(r1, w0, pv4[s * 8 + 2], pv4[s * 8 + 3], o + 8);
            acc8(r2, w1, pv4[s * 8 + 4], pv4[s * 8 + 5], o + 16);
            acc8(r3, w1, pv4[s * 8 + 6], pv4[s * 8 + 7], o + 24);
        } else { wi0 += w0; wi1 += w1; }
    }
    #pragma unroll
    for (int c = 0; c < 16; ++c) o[c] = fmaf(wi0, Wd[4256 + c], o[c]);
    #pragma unroll
    for (int c = 16; c < 32; ++c) o[c] = fmaf(wi1, Wd[4256 + c], o[c]);

    // out = o @ out_w.T + out_b, weights via uniform float4 reads
    float out[32];
    const float4* ob4 = (const float4*)&Wd[4192];
    #pragma unroll
    for (int i4 = 0; i4 < 8; ++i4) {
        const float4 t = ob4[i4];
        out[i4*4+0] = t.x; out[i4*4+1] = t.y;
        out[i4*4+2] = t.z; out[i4*4+3] = t.w;
    }
    #pragma unroll
    for (int j = 0; j < 32; ++j) {
        const float oj = o[j];
        const float4* wr = (const float4*)&Wd[3072 + j * 32];
        #pragma unroll
        for (int i4 = 0; i4 < 8; ++i4) {
            const float4 w = wr[i4];
            out[i4*4+0] = fmaf(oj, w.x, out[i4*4+0]);
            out[i4*4+1] = fmaf(oj, w.y, out[i4*4+1]);
            out[i4*4+2] = fmaf(oj, w.z, out[i4*4+2]);
            out[i4*4+3] = fmaf(oj, w.w, out[i4*4+3]);
        }
    }
    store32bf(res + (size_t)n * CC, out);
}

__launch_bounds__(256)
__global__ void canvas_kernel(const int* __restrict__ lut, const __hip_bfloat16* __restrict__ resArr,
                              const int* __restrict__ flag, void* __restrict__ out) {
    const int F = *flag;
    const int tile = blockIdx.x % (HWP / 64);
    const int rem  = blockIdx.x / (HWP / 64);
    const int b = rem & 3;
    const int d = rem >> 2;
    const int* lutq = lut + (size_t)(d * BB + b) * HWP + (size_t)tile * 64;
    __shared__ int ls[64];
    __shared__ float st[64 * 33];
    const int t = threadIdx.x;
    if (t < 16) ((int4*)ls)[t] = ((const int4*)lutq)[t];
    __syncthreads();

    const __hip_bfloat16* res = resArr + (size_t)(d * BB + b) * NN * CC;
    {
        const int r = t >> 2, q = t & 3;
        const int idx = ls[r];
        uint4 raw = make_uint4(0u, 0u, 0u, 0u);
        if (idx >= 0) raw = *(const uint4*)(res + (size_t)idx * CC + q * 8);
        float* dst = &st[r * 33 + q * 8];
        dst[0] = blo(raw.x); dst[1] = bhi(raw.x);
        dst[2] = blo(raw.y); dst[3] = bhi(raw.y);
        dst[4] = blo(raw.z); dst[5] = bhi(raw.z);
        dst[6] = blo(raw.w); dst[7] = bhi(raw.w);
    }
    __syncthreads();

    const int c = t >> 3, g = t & 7;
    float v[8];
    #pragma unroll
    for (int j = 0; j < 8; ++j) v[j] = st[(8 * g + j) * 33 + c];
    const size_t obase = ((size_t)(d * BB + b) * CC + c) * HWP + (size_t)tile * 64 + 8 * g;
    if (F) {
        float* ob = (float*)out + obase;
        ((float4*)ob)[0] = make_float4(v[0], v[1], v[2], v[3]);
        ((float4*)ob)[1] = make_float4(v[4], v[5], v[6], v[7]);
    } else {
        __hip_bfloat16* ob = (__hip_bfloat16*)out + obase;
        __hip_bfloat16 h[8];
        #pragma unroll
        for (int j = 0; j < 8; ++j) h[j] = __float2bfloat16(v[j]);
        *(uint4*)ob = *(const uint4*)h;
    }
}

extern "C" void kernel_launch(void* const* d_in, const int* in_sizes, int n_in,
                              void* d_out, int out_size, void* d_ws, size_t ws_size,
                              hipStream_t stream) {
    (void)in_sizes; (void)n_in; (void)out_size; (void)ws_size;
    const void* li_feats = d_in[0];
    const void* ra_feats = d_in[1];
    const int* li_coors = (const int*)d_in[2];
    const int* ra_coors = (const int*)d_in[3];
    const void* li_nw = d_in[4];
    const void* li_nb = d_in[5];
    const void* ra_nw = d_in[6];
    const void* ra_nb = d_in[7];

    char* ws = (char*)d_ws;
    int*   flag = (int*)ws;
    float* wsW  = (float*)(ws + 512);
    int*   lut  = (int*)(ws + 40960);
    __hip_bfloat16* qArr = (__hip_bfloat16*)(ws + 6463488);
    __hip_bfloat16* kArr = (__hip_bfloat16*)(ws + 16703488);
    __hip_bfloat16* vArr = (__hip_bfloat16*)(ws + 26943488);
    __hip_bfloat16* rArr = (__hip_bfloat16*)(ws + 37183488);  // un-aliased (ws is ~822 MB)

    hipMemsetAsync(lut, 0xFF, (size_t)2 * BB * HWP * sizeof(int), stream);
    const int buildBlocks = (2 * BB * NN + 255) / 256;
    prep_build<<<2 + buildBlocks, 256, 0, stream>>>(d_in[8], d_in[9], d_in[10], d_in[11], d_in[12], d_in[13],
                                                    d_in[14], d_in[15], d_in[16], d_in[17],
                                                    d_in[18], d_in[19], d_in[20], d_in[21],
                                                    li_feats, li_coors, ra_coors, lut, flag, wsW);
    project_kernel<<<8 * NPB, 256, 0, stream>>>(li_feats, ra_feats, li_nw, li_nb, ra_nw, ra_nb,
                                                flag, wsW, qArr, kArr, vArr);
    attn_kernel<<<8 * NPB, 256, 0, stream>>>(li_coors, ra_coors, wsW, lut, qArr, kArr, vArr, rArr);
    canvas_kernel<<<2 * BB * (HWP / 64), 256, 0, stream>>>(lut, rArr, flag, d_out);
}